// Round 1
// baseline (1115.715 us; speedup 1.0000x reference)
//
#include <hip/hip_runtime.h>
#include <hip/hip_bf16.h>

// GraphAE: pseudo == 0  =>  spline basis c[:,k] = delta(k,0); only W[0] matters.
// Pipeline:
//   deg/CSR build -> agg1 = mean_x -> h = relu(agg1@W1_0 + x@root1 + b1)
//   agg2 = mean_h -> z = agg2@W2_0 + h@root2 + b2
//   h2 = relu(z@dec_w1 + db1) -> out = h2@dec_w2 + db2

#define THREADS 256

__global__ void count_edges(const int* __restrict__ dst, int* __restrict__ cnt, int E) {
    int e = blockIdx.x * blockDim.x + threadIdx.x;
    if (e < E) atomicAdd(&cnt[dst[e]], 1);
}

// single-block exclusive scan over n ints (n up to ~a few hundred k)
__global__ void scan_exclusive(const int* __restrict__ cnt, int* __restrict__ offs, int n) {
    __shared__ int smem[1024];
    __shared__ int carry_sh;
    if (threadIdx.x == 0) carry_sh = 0;
    __syncthreads();
    for (int base = 0; base < n; base += 1024) {
        int i = base + (int)threadIdx.x;
        int v = (i < n) ? cnt[i] : 0;
        smem[threadIdx.x] = v;
        __syncthreads();
        for (int off = 1; off < 1024; off <<= 1) {
            int t = (threadIdx.x >= (unsigned)off) ? smem[threadIdx.x - off] : 0;
            __syncthreads();
            smem[threadIdx.x] += t;
            __syncthreads();
        }
        int incl = smem[threadIdx.x];
        int carry = carry_sh;
        if (i < n) offs[i] = carry + incl - v;   // exclusive
        __syncthreads();
        if (threadIdx.x == 0) carry_sh = carry + smem[1023];
        __syncthreads();
    }
    if (threadIdx.x == 0) offs[n] = carry_sh;
}

__global__ void fill_csr(const int* __restrict__ src, const int* __restrict__ dst,
                         const int* __restrict__ offs, int* __restrict__ cursor,
                         int* __restrict__ esrc, int E) {
    int e = blockIdx.x * blockDim.x + threadIdx.x;
    if (e < E) {
        int d = dst[e];
        int p = atomicAdd(&cursor[d], 1);
        esrc[offs[d] + p] = src[e];
    }
}

__global__ void inv_deg_kernel(const int* __restrict__ cnt, float* __restrict__ invd, int n) {
    int i = blockIdx.x * blockDim.x + threadIdx.x;
    if (i < n) invd[i] = 1.0f / (float)max(cnt[i], 1);
}

// mean-aggregate 64-wide rows: 4 nodes per 256-thread block (one wave each)
__global__ void agg_mean_64(const float* __restrict__ x, const int* __restrict__ esrc,
                            const int* __restrict__ offs, const float* __restrict__ invd,
                            float* __restrict__ agg, int n) {
    int node = blockIdx.x * 4 + (threadIdx.x >> 6);
    int f = threadIdx.x & 63;
    if (node >= n) return;
    int s = offs[node], e = offs[node + 1];
    float acc = 0.f;
    for (int j = s; j < e; ++j) {
        int sn = esrc[j];
        acc += x[sn * 64 + f];
    }
    agg[node * 64 + f] = acc * invd[node];
}

// mean-aggregate 256-wide rows: 1 node per 256-thread block
__global__ void agg_mean_256(const float* __restrict__ h, const int* __restrict__ esrc,
                             const int* __restrict__ offs, const float* __restrict__ invd,
                             float* __restrict__ agg, int n) {
    int node = blockIdx.x;
    if (node >= n) return;
    int f = threadIdx.x;
    int s = offs[node], e = offs[node + 1];
    float acc = 0.f;
    for (int j = s; j < e; ++j) acc += h[esrc[j] * 256 + f];
    agg[node * 256 + f] = acc * invd[node];
}

// h = relu(agg1@W0 + x@root + b)   [64 -> 256], one node per block
__global__ void gemm_h_kernel(const float* __restrict__ agg1, const float* __restrict__ x,
                              const float* __restrict__ W0, const float* __restrict__ root,
                              const float* __restrict__ b, float* __restrict__ h, int n) {
    __shared__ float arow[64];
    __shared__ float xrow[64];
    int node = blockIdx.x;
    if (node >= n) return;
    int m = threadIdx.x;
    if (m < 64) arow[m] = agg1[node * 64 + m];
    else if (m < 128) xrow[m - 64] = x[node * 64 + (m - 64)];
    __syncthreads();
    float acc = b[m];
#pragma unroll 8
    for (int k = 0; k < 64; ++k)
        acc += arow[k] * W0[k * 256 + m] + xrow[k] * root[k * 256 + m];
    h[node * 256 + m] = fmaxf(acc, 0.f);
}

// z = agg2@W0 + h@root + b   [256 -> 64], one node per block, split-k x4
__global__ void gemm_z_kernel(const float* __restrict__ agg2, const float* __restrict__ h,
                              const float* __restrict__ W0, const float* __restrict__ root,
                              const float* __restrict__ b, float* __restrict__ z, int n) {
    __shared__ float arow[256];
    __shared__ float hrow[256];
    __shared__ float part[256];
    int node = blockIdx.x;
    if (node >= n) return;
    int t = threadIdx.x;
    arow[t] = agg2[node * 256 + t];
    hrow[t] = h[node * 256 + t];
    __syncthreads();
    int m = t & 63, kg = t >> 6;
    float acc = 0.f;
#pragma unroll 8
    for (int k = kg * 64; k < kg * 64 + 64; ++k)
        acc += arow[k] * W0[k * 64 + m] + hrow[k] * root[k * 64 + m];
    part[t] = acc;
    __syncthreads();
    if (t < 64)
        z[node * 64 + t] = part[t] + part[t + 64] + part[t + 128] + part[t + 192] + b[t];
}

// h2 = relu(z@W + b)   [64 -> 256], one node per block
__global__ void gemm_h2_kernel(const float* __restrict__ z, const float* __restrict__ W,
                               const float* __restrict__ b, float* __restrict__ h2, int n) {
    __shared__ float zrow[64];
    int node = blockIdx.x;
    if (node >= n) return;
    int m = threadIdx.x;
    if (m < 64) zrow[m] = z[node * 64 + m];
    __syncthreads();
    float acc = b[m];
#pragma unroll 8
    for (int k = 0; k < 64; ++k) acc += zrow[k] * W[k * 256 + m];
    h2[node * 256 + m] = fmaxf(acc, 0.f);
}

// out = h2@W + b   [256 -> 64], one node per block, split-k x4
__global__ void gemm_out_kernel(const float* __restrict__ h2, const float* __restrict__ W,
                                const float* __restrict__ b, float* __restrict__ out, int n) {
    __shared__ float hrow[256];
    __shared__ float part[256];
    int node = blockIdx.x;
    if (node >= n) return;
    int t = threadIdx.x;
    hrow[t] = h2[node * 256 + t];
    __syncthreads();
    int m = t & 63, kg = t >> 6;
    float acc = 0.f;
#pragma unroll 8
    for (int k = kg * 64; k < kg * 64 + 64; ++k)
        acc += hrow[k] * W[k * 64 + m];
    part[t] = acc;
    __syncthreads();
    if (t < 64)
        out[node * 64 + t] = part[t] + part[t + 64] + part[t + 128] + part[t + 192] + b[t];
}

extern "C" void kernel_launch(void* const* d_in, const int* in_sizes, int n_in,
                              void* d_out, int out_size, void* d_ws, size_t ws_size,
                              hipStream_t stream) {
    const float* x      = (const float*)d_in[0];
    const int*   ei     = (const int*)d_in[1];
    const float* W1     = (const float*)d_in[2];   // (8,64,256) -> W1[0] = first 16384
    const float* root1  = (const float*)d_in[3];
    const float* b1     = (const float*)d_in[4];
    const float* W2     = (const float*)d_in[5];   // (8,256,64) -> W2[0] = first 16384
    const float* root2  = (const float*)d_in[6];
    const float* b2     = (const float*)d_in[7];
    const float* dw1    = (const float*)d_in[8];
    const float* db1    = (const float*)d_in[9];
    const float* dw2    = (const float*)d_in[10];
    const float* db2    = (const float*)d_in[11];
    float* out = (float*)d_out;

    const int N = in_sizes[0] / 64;
    const int E = in_sizes[1] / 2;
    const int* srcv = ei;
    const int* dstv = ei + E;

    // workspace carve-up (256B aligned)
    char* ws = (char*)d_ws;
    auto alloc = [&](size_t bytes) -> void* {
        void* p = (void*)ws;
        ws += (bytes + 255) & ~(size_t)255;
        return p;
    };
    int*   cnt    = (int*)alloc((size_t)N * 4);
    int*   cursor = (int*)alloc((size_t)N * 4);
    int*   offs   = (int*)alloc((size_t)(N + 1) * 4);
    float* invd   = (float*)alloc((size_t)N * 4);
    int*   esrc   = (int*)alloc((size_t)E * 4);
    float* agg1   = (float*)alloc((size_t)N * 64 * 4);
    float* h      = (float*)alloc((size_t)N * 256 * 4);
    float* agg2   = (float*)alloc((size_t)N * 256 * 4);
    float* z      = agg1;   // agg1 dead after gemm_h
    float* h2     = h;      // h dead after gemm_z

    hipMemsetAsync(cnt, 0, (size_t)N * 4, stream);
    hipMemsetAsync(cursor, 0, (size_t)N * 4, stream);

    int eb = (E + THREADS - 1) / THREADS;
    int nb = (N + THREADS - 1) / THREADS;

    count_edges<<<eb, THREADS, 0, stream>>>(dstv, cnt, E);
    scan_exclusive<<<1, 1024, 0, stream>>>(cnt, offs, N);
    fill_csr<<<eb, THREADS, 0, stream>>>(srcv, dstv, offs, cursor, esrc, E);
    inv_deg_kernel<<<nb, THREADS, 0, stream>>>(cnt, invd, N);

    agg_mean_64<<<(N + 3) / 4, THREADS, 0, stream>>>(x, esrc, offs, invd, agg1, N);
    gemm_h_kernel<<<N, THREADS, 0, stream>>>(agg1, x, W1, root1, b1, h, N);
    agg_mean_256<<<N, THREADS, 0, stream>>>(h, esrc, offs, invd, agg2, N);
    gemm_z_kernel<<<N, THREADS, 0, stream>>>(agg2, h, W2, root2, b2, z, N);
    gemm_h2_kernel<<<N, THREADS, 0, stream>>>(z, dw1, db1, h2, N);
    gemm_out_kernel<<<N, THREADS, 0, stream>>>(h2, dw2, db2, out, N);
}

// Round 2
// 676.471 us; speedup vs baseline: 1.6493x; 1.6493x over previous
//
#include <hip/hip_runtime.h>
#include <hip/hip_bf16.h>

// GraphAE: pseudo == 0  =>  spline basis c[:,k] = delta(k,0); only W[0] matters.
//   deg/CSR -> agg1 = mean_x -> h = relu(agg1@W1_0 + x@root1 + b1)   (h stored in Acat[:,256:512])
//   agg2 = mean_h (into Acat[:,0:256]) -> z = Acat@[W2_0;root2] + b2
//   h2 = relu(z@dw1 + db1) -> out = h2@dec_w2 + db2
// GEMMs are register-blocked: A staged transposed in LDS ([k][row], stride 68 keeps
// 16B alignment + conflict-free reads), weights streamed coalesced from L2.

#define THREADS 256

__device__ __forceinline__ void fma4(float4& acc, float a, const float4& w) {
    acc.x += a * w.x; acc.y += a * w.y; acc.z += a * w.z; acc.w += a * w.w;
}

__global__ void count_edges(const int* __restrict__ dst, int* __restrict__ cnt, int E) {
    int e = blockIdx.x * blockDim.x + threadIdx.x;
    if (e < E) atomicAdd(&cnt[dst[e]], 1);
}

__global__ void scan_exclusive(const int* __restrict__ cnt, int* __restrict__ offs, int n) {
    __shared__ int smem[1024];
    __shared__ int carry_sh;
    if (threadIdx.x == 0) carry_sh = 0;
    __syncthreads();
    for (int base = 0; base < n; base += 1024) {
        int i = base + (int)threadIdx.x;
        int v = (i < n) ? cnt[i] : 0;
        smem[threadIdx.x] = v;
        __syncthreads();
        for (int off = 1; off < 1024; off <<= 1) {
            int t = (threadIdx.x >= (unsigned)off) ? smem[threadIdx.x - off] : 0;
            __syncthreads();
            smem[threadIdx.x] += t;
            __syncthreads();
        }
        int incl = smem[threadIdx.x];
        int carry = carry_sh;
        if (i < n) offs[i] = carry + incl - v;
        __syncthreads();
        if (threadIdx.x == 0) carry_sh = carry + smem[1023];
        __syncthreads();
    }
    if (threadIdx.x == 0) offs[n] = carry_sh;
}

__global__ void fill_csr(const int* __restrict__ src, const int* __restrict__ dst,
                         const int* __restrict__ offs, int* __restrict__ cursor,
                         int* __restrict__ esrc, int E) {
    int e = blockIdx.x * blockDim.x + threadIdx.x;
    if (e < E) {
        int d = dst[e];
        int p = atomicAdd(&cursor[d], 1);
        esrc[offs[d] + p] = src[e];
    }
}

__global__ void inv_deg_kernel(const int* __restrict__ cnt, float* __restrict__ invd, int n) {
    int i = blockIdx.x * blockDim.x + threadIdx.x;
    if (i < n) invd[i] = 1.0f / (float)max(cnt[i], 1);
}

// mean-aggregate 64-wide rows: 4 nodes per block (one wave each), scalar coalesced
__global__ void agg_mean_64(const float* __restrict__ x, const int* __restrict__ esrc,
                            const int* __restrict__ offs, const float* __restrict__ invd,
                            float* __restrict__ agg, int n) {
    int node = blockIdx.x * 4 + (threadIdx.x >> 6);
    int f = threadIdx.x & 63;
    if (node >= n) return;
    int s = offs[node], e = offs[node + 1];
    float acc = 0.f;
    for (int j = s; j < e; ++j) acc += x[(size_t)esrc[j] * 64 + f];
    agg[(size_t)node * 64 + f] = acc * invd[node];
}

// mean-aggregate 256-wide rows (float4): 4 nodes/block, one wave each.
// hsrc = Acat + 256 (ld 512); writes agg into Acat cols 0..255 (ld 512).
__global__ void agg_mean_256v(const float* __restrict__ hsrc, float* __restrict__ aggdst,
                              const int* __restrict__ esrc, const int* __restrict__ offs,
                              const float* __restrict__ invd, int n) {
    int node = blockIdx.x * 4 + (threadIdx.x >> 6);
    int l = threadIdx.x & 63;
    if (node >= n) return;
    int s = offs[node], e = offs[node + 1];
    float ax = 0.f, ay = 0.f, az = 0.f, aw = 0.f;
    for (int j = s; j < e; ++j) {
        const float4 v = *(const float4*)(hsrc + (size_t)esrc[j] * 512 + l * 4);
        ax += v.x; ay += v.y; az += v.z; aw += v.w;
    }
    float iv = invd[node];
    float4 o; o.x = ax * iv; o.y = ay * iv; o.z = az * iv; o.w = aw * iv;
    *(float4*)(aggdst + (size_t)node * 512 + l * 4) = o;
}

// C[m, 0:256] = act( A0[m,0:64]@W0 + (A1? A1[m,0:64]@W1 : 0) + bias )
// 64-node tile, 256 threads; thread = (tn in [0,64)) x (tm in [0,4)): 4 cols x 16 rows.
__global__ __launch_bounds__(256) void gemm_n256(
    const float* __restrict__ A0, int lda0,
    const float* __restrict__ A1, int lda1,
    const float* __restrict__ W0, const float* __restrict__ W1,
    const float* __restrict__ bias,
    float* __restrict__ C, int ldc, int n, int do_relu)
{
    __shared__ float As[128][68];
    const int m0 = blockIdx.x * 64;
    const int t = threadIdx.x;

    for (int i = t; i < 64 * 16; i += 256) {
        int row = i >> 4, c4 = (i & 15) * 4;
        int gr = m0 + row;
        float4 v = make_float4(0.f, 0.f, 0.f, 0.f);
        if (gr < n) v = *(const float4*)(A0 + (size_t)gr * lda0 + c4);
        As[c4 + 0][row] = v.x; As[c4 + 1][row] = v.y;
        As[c4 + 2][row] = v.z; As[c4 + 3][row] = v.w;
    }
    if (A1) {
        for (int i = t; i < 64 * 16; i += 256) {
            int row = i >> 4, c4 = (i & 15) * 4;
            int gr = m0 + row;
            float4 v = make_float4(0.f, 0.f, 0.f, 0.f);
            if (gr < n) v = *(const float4*)(A1 + (size_t)gr * lda1 + c4);
            As[64 + c4 + 0][row] = v.x; As[64 + c4 + 1][row] = v.y;
            As[64 + c4 + 2][row] = v.z; As[64 + c4 + 3][row] = v.w;
        }
    }
    __syncthreads();

    const int tn = t & 63, tm = t >> 6;
    const int colb = tn * 4, rowb = tm * 16;

    float4 acc[16];
#pragma unroll
    for (int r = 0; r < 16; ++r) acc[r] = make_float4(0.f, 0.f, 0.f, 0.f);

#pragma unroll 4
    for (int k = 0; k < 64; ++k) {
        float4 w = *(const float4*)(W0 + (k << 8) + colb);
        const float* ar = &As[k][rowb];
#pragma unroll
        for (int r = 0; r < 16; ++r) fma4(acc[r], ar[r], w);
    }
    if (A1) {
#pragma unroll 4
        for (int k = 0; k < 64; ++k) {
            float4 w = *(const float4*)(W1 + (k << 8) + colb);
            const float* ar = &As[64 + k][rowb];
#pragma unroll
            for (int r = 0; r < 16; ++r) fma4(acc[r], ar[r], w);
        }
    }

    float4 bv = *(const float4*)(bias + colb);
#pragma unroll
    for (int r = 0; r < 16; ++r) {
        int gr = m0 + rowb + r;
        if (gr < n) {
            float4 o;
            o.x = acc[r].x + bv.x; o.y = acc[r].y + bv.y;
            o.z = acc[r].z + bv.z; o.w = acc[r].w + bv.w;
            if (do_relu) {
                o.x = fmaxf(o.x, 0.f); o.y = fmaxf(o.y, 0.f);
                o.z = fmaxf(o.z, 0.f); o.w = fmaxf(o.w, 0.f);
            }
            *(float4*)(C + (size_t)gr * ldc + colb) = o;
        }
    }
}

// C[m, 0:64] = A[m,0:K] @ Wcat + bias, Wcat = W0 for k<ksplit else W1[k-ksplit].
// 64-node tile, 128 threads; thread = (tn in [0,16)) x (tm in [0,8)): 4 cols x 8 rows.
__global__ __launch_bounds__(128) void gemm_n64(
    const float* __restrict__ A, int lda, int K,
    const float* __restrict__ W0, const float* __restrict__ W1, int ksplit,
    const float* __restrict__ bias,
    float* __restrict__ C, int ldc, int n)
{
    __shared__ float As[64][68];
    const int m0 = blockIdx.x * 64;
    const int t = threadIdx.x;
    const int tn = t & 15, tm = t >> 4;
    const int colb = tn * 4, rowb = tm * 8;

    float4 acc[8];
#pragma unroll
    for (int r = 0; r < 8; ++r) acc[r] = make_float4(0.f, 0.f, 0.f, 0.f);

    for (int kc = 0; kc < K; kc += 64) {
        __syncthreads();
        for (int i = t; i < 64 * 16; i += 128) {
            int row = i >> 4, c4 = (i & 15) * 4;
            int gr = m0 + row;
            float4 v = make_float4(0.f, 0.f, 0.f, 0.f);
            if (gr < n) v = *(const float4*)(A + (size_t)gr * lda + kc + c4);
            As[c4 + 0][row] = v.x; As[c4 + 1][row] = v.y;
            As[c4 + 2][row] = v.z; As[c4 + 3][row] = v.w;
        }
        __syncthreads();
        const float* Wb = (kc < ksplit) ? (W0 + kc * 64) : (W1 + (kc - ksplit) * 64);
#pragma unroll 4
        for (int k = 0; k < 64; ++k) {
            float4 w = *(const float4*)(Wb + (k << 6) + colb);
            const float* ar = &As[k][rowb];
#pragma unroll
            for (int r = 0; r < 8; ++r) fma4(acc[r], ar[r], w);
        }
    }

    float4 bv = *(const float4*)(bias + colb);
#pragma unroll
    for (int r = 0; r < 8; ++r) {
        int gr = m0 + rowb + r;
        if (gr < n) {
            float4 o;
            o.x = acc[r].x + bv.x; o.y = acc[r].y + bv.y;
            o.z = acc[r].z + bv.z; o.w = acc[r].w + bv.w;
            *(float4*)(C + (size_t)gr * ldc + colb) = o;
        }
    }
}

extern "C" void kernel_launch(void* const* d_in, const int* in_sizes, int n_in,
                              void* d_out, int out_size, void* d_ws, size_t ws_size,
                              hipStream_t stream) {
    const float* x      = (const float*)d_in[0];
    const int*   ei     = (const int*)d_in[1];
    const float* W1     = (const float*)d_in[2];   // (8,64,256): W1[0] = first 16384
    const float* root1  = (const float*)d_in[3];
    const float* b1     = (const float*)d_in[4];
    const float* W2     = (const float*)d_in[5];   // (8,256,64): W2[0] = first 16384
    const float* root2  = (const float*)d_in[6];
    const float* b2     = (const float*)d_in[7];
    const float* dw1    = (const float*)d_in[8];
    const float* db1    = (const float*)d_in[9];
    const float* dw2    = (const float*)d_in[10];
    const float* db2    = (const float*)d_in[11];
    float* out = (float*)d_out;

    const int N = in_sizes[0] / 64;
    const int E = in_sizes[1] / 2;
    const int* srcv = ei;
    const int* dstv = ei + E;

    char* ws = (char*)d_ws;
    auto alloc = [&](size_t bytes) -> void* {
        void* p = (void*)ws;
        ws += (bytes + 255) & ~(size_t)255;
        return p;
    };
    int*   cnt    = (int*)alloc((size_t)N * 4);
    int*   cursor = (int*)alloc((size_t)N * 4);
    int*   offs   = (int*)alloc((size_t)(N + 1) * 4);
    float* invd   = (float*)alloc((size_t)N * 4);
    int*   esrc   = (int*)alloc((size_t)E * 4);
    float* agg1   = (float*)alloc((size_t)N * 64 * 4);   // also holds z (dead after gemm1->used as z)
    float* Acat   = (float*)alloc((size_t)N * 512 * 4);  // cols 0:256 agg2, 256:512 h; reused as h2
    float* z      = agg1;                                 // agg1 dead after gemm1
    float* h2     = Acat;                                 // Acat dead after gemm2 (ld 256)

    hipMemsetAsync(cnt, 0, (size_t)N * 4, stream);
    hipMemsetAsync(cursor, 0, (size_t)N * 4, stream);

    int eb = (E + THREADS - 1) / THREADS;
    int nb = (N + THREADS - 1) / THREADS;
    int gb = (N + 63) / 64;

    count_edges<<<eb, THREADS, 0, stream>>>(dstv, cnt, E);
    scan_exclusive<<<1, 1024, 0, stream>>>(cnt, offs, N);
    fill_csr<<<eb, THREADS, 0, stream>>>(srcv, dstv, offs, cursor, esrc, E);
    inv_deg_kernel<<<nb, THREADS, 0, stream>>>(cnt, invd, N);

    // layer 1
    agg_mean_64<<<(N + 3) / 4, THREADS, 0, stream>>>(x, esrc, offs, invd, agg1, N);
    gemm_n256<<<gb, 256, 0, stream>>>(agg1, 64, x, 64, W1, root1, b1,
                                      Acat + 256, 512, N, 1);        // h -> Acat[:,256:512]
    // layer 2
    agg_mean_256v<<<(N + 3) / 4, THREADS, 0, stream>>>(Acat + 256, Acat, esrc, offs, invd, N);
    gemm_n64<<<gb, 128, 0, stream>>>(Acat, 512, 512, W2, root2, 256, b2, z, 64, N);
    // decoder
    gemm_n256<<<gb, 256, 0, stream>>>(z, 64, nullptr, 0, dw1, nullptr, db1, h2, 256, N, 1);
    gemm_n64<<<gb, 128, 0, stream>>>(h2, 256, 256, dw2, dw2, 1 << 30, db2, out, 64, N);
}

// Round 3
// 490.272 us; speedup vs baseline: 2.2757x; 1.3798x over previous
//
#include <hip/hip_runtime.h>
#include <hip/hip_bf16.h>

// GraphAE: pseudo == 0  =>  spline basis c[:,k] = delta(k,0); only W[0] matters.
// Linearization: mean(h[src]) @ W2_0 == mean(h[src] @ W2_0)  -> project to 64-dim
// BEFORE the gather (4x less gather traffic, table becomes L2/L3-resident).
//   CSR -> agg1 = mean_x -> h = relu(agg1@W1_0 + x@root1 + b1)
//   hwroot[:,0:64] = h@W2_0, hwroot[:,64:128] = h@root2     (one fused dual GEMM)
//   z = mean(hw[src]) + hroot + b2                           (gather + epilogue)
//   h2 = relu(z@dw1 + db1) -> out = h2@dec_w2 + db2

#define THREADS 256

__device__ __forceinline__ void fma4(float4& acc, float a, const float4& w) {
    acc.x += a * w.x; acc.y += a * w.y; acc.z += a * w.z; acc.w += a * w.w;
}

__global__ void count_edges(const int* __restrict__ dst, int* __restrict__ cnt, int E) {
    int e = blockIdx.x * blockDim.x + threadIdx.x;
    if (e < E) atomicAdd(&cnt[dst[e]], 1);
}

// ---- hierarchical exclusive scan: 1024 elems/block (256 thr x 4) ----
__global__ void scan_block(const int* __restrict__ cnt, int* __restrict__ offs,
                           int* __restrict__ bsum, int n) {
    __shared__ int tsum[256];
    int t = threadIdx.x;
    int base = blockIdx.x * 1024 + t * 4;
    int v0 = (base + 0 < n) ? cnt[base + 0] : 0;
    int v1 = (base + 1 < n) ? cnt[base + 1] : 0;
    int v2 = (base + 2 < n) ? cnt[base + 2] : 0;
    int v3 = (base + 3 < n) ? cnt[base + 3] : 0;
    int s = v0 + v1 + v2 + v3;
    tsum[t] = s;
    __syncthreads();
    for (int off = 1; off < 256; off <<= 1) {
        int xv = (t >= off) ? tsum[t - off] : 0;
        __syncthreads();
        tsum[t] += xv;
        __syncthreads();
    }
    int excl = tsum[t] - s;
    if (base + 0 < n) offs[base + 0] = excl;
    if (base + 1 < n) offs[base + 1] = excl + v0;
    if (base + 2 < n) offs[base + 2] = excl + v0 + v1;
    if (base + 3 < n) offs[base + 3] = excl + v0 + v1 + v2;
    if (t == 255) bsum[blockIdx.x] = tsum[255];
}

__global__ void scan_partials(int* __restrict__ bsum, int* __restrict__ total, int nb) {
    __shared__ int sm[256];
    int t = threadIdx.x;
    int v = (t < nb) ? bsum[t] : 0;
    sm[t] = v;
    __syncthreads();
    for (int off = 1; off < 256; off <<= 1) {
        int xv = (t >= off) ? sm[t - off] : 0;
        __syncthreads();
        sm[t] += xv;
        __syncthreads();
    }
    if (t < nb) bsum[t] = sm[t] - v;   // exclusive
    if (t == 255) *total = sm[255];
}

__global__ void scan_add(int* __restrict__ offs, const int* __restrict__ bsum,
                         const int* __restrict__ total, int n) {
    int i = blockIdx.x * blockDim.x + threadIdx.x;
    if (i < n) offs[i] += bsum[i >> 10];
    if (i == 0) offs[n] = *total;
}

__global__ void fill_csr(const int* __restrict__ src, const int* __restrict__ dst,
                         const int* __restrict__ offs, int* __restrict__ cursor,
                         int* __restrict__ esrc, int E) {
    int e = blockIdx.x * blockDim.x + threadIdx.x;
    if (e < E) {
        int d = dst[e];
        int p = atomicAdd(&cursor[d], 1);
        esrc[offs[d] + p] = src[e];
    }
}

__global__ void inv_deg_kernel(const int* __restrict__ cnt, float* __restrict__ invd, int n) {
    int i = blockIdx.x * blockDim.x + threadIdx.x;
    if (i < n) invd[i] = 1.0f / (float)max(cnt[i], 1);
}

// mean-aggregate 64-wide rows (x): 4 nodes/block, one wave each, 4x edge unroll
__global__ void agg_mean_64u(const float* __restrict__ x, const int* __restrict__ esrc,
                             const int* __restrict__ offs, const float* __restrict__ invd,
                             float* __restrict__ agg, int n) {
    int node = blockIdx.x * 4 + (threadIdx.x >> 6);
    int l = threadIdx.x & 63;
    if (node >= n) return;
    int s = offs[node], e = offs[node + 1];
    float a0 = 0.f, a1 = 0.f, a2 = 0.f, a3 = 0.f;
    int j = s;
    for (; j + 4 <= e; j += 4) {
        int i0 = esrc[j], i1 = esrc[j + 1], i2 = esrc[j + 2], i3 = esrc[j + 3];
        a0 += x[(size_t)i0 * 64 + l];
        a1 += x[(size_t)i1 * 64 + l];
        a2 += x[(size_t)i2 * 64 + l];
        a3 += x[(size_t)i3 * 64 + l];
    }
    for (; j < e; ++j) a0 += x[(size_t)esrc[j] * 64 + l];
    agg[(size_t)node * 64 + l] = (a0 + a1 + a2 + a3) * invd[node];
}

// z = mean(hw[src]) + hroot + b2 ; hwroot is N x 128 (cols 0:64 hw, 64:128 hroot)
__global__ void agg_z(const float* __restrict__ hwroot, const int* __restrict__ esrc,
                      const int* __restrict__ offs, const float* __restrict__ invd,
                      const float* __restrict__ b2, float* __restrict__ z, int n) {
    int node = blockIdx.x * 4 + (threadIdx.x >> 6);
    int l = threadIdx.x & 63;
    if (node >= n) return;
    int s = offs[node], e = offs[node + 1];
    float a0 = 0.f, a1 = 0.f, a2 = 0.f, a3 = 0.f;
    int j = s;
    for (; j + 4 <= e; j += 4) {
        int i0 = esrc[j], i1 = esrc[j + 1], i2 = esrc[j + 2], i3 = esrc[j + 3];
        a0 += hwroot[(size_t)i0 * 128 + l];
        a1 += hwroot[(size_t)i1 * 128 + l];
        a2 += hwroot[(size_t)i2 * 128 + l];
        a3 += hwroot[(size_t)i3 * 128 + l];
    }
    for (; j < e; ++j) a0 += hwroot[(size_t)esrc[j] * 128 + l];
    z[(size_t)node * 64 + l] =
        (a0 + a1 + a2 + a3) * invd[node] + hwroot[(size_t)node * 128 + 64 + l] + b2[l];
}

// C[m, 0:256] = act( A0[m,0:64]@W0 + (A1? A1[m,0:64]@W1 : 0) + bias )
__global__ __launch_bounds__(256) void gemm_n256(
    const float* __restrict__ A0, int lda0,
    const float* __restrict__ A1, int lda1,
    const float* __restrict__ W0, const float* __restrict__ W1,
    const float* __restrict__ bias,
    float* __restrict__ C, int ldc, int n, int do_relu)
{
    __shared__ float As[128][68];
    const int m0 = blockIdx.x * 64;
    const int t = threadIdx.x;

    for (int i = t; i < 64 * 16; i += 256) {
        int row = i >> 4, c4 = (i & 15) * 4;
        int gr = m0 + row;
        float4 v = make_float4(0.f, 0.f, 0.f, 0.f);
        if (gr < n) v = *(const float4*)(A0 + (size_t)gr * lda0 + c4);
        As[c4 + 0][row] = v.x; As[c4 + 1][row] = v.y;
        As[c4 + 2][row] = v.z; As[c4 + 3][row] = v.w;
    }
    if (A1) {
        for (int i = t; i < 64 * 16; i += 256) {
            int row = i >> 4, c4 = (i & 15) * 4;
            int gr = m0 + row;
            float4 v = make_float4(0.f, 0.f, 0.f, 0.f);
            if (gr < n) v = *(const float4*)(A1 + (size_t)gr * lda1 + c4);
            As[64 + c4 + 0][row] = v.x; As[64 + c4 + 1][row] = v.y;
            As[64 + c4 + 2][row] = v.z; As[64 + c4 + 3][row] = v.w;
        }
    }
    __syncthreads();

    const int tn = t & 63, tm = t >> 6;
    const int colb = tn * 4, rowb = tm * 16;

    float4 acc[16];
#pragma unroll
    for (int r = 0; r < 16; ++r) acc[r] = make_float4(0.f, 0.f, 0.f, 0.f);

#pragma unroll 4
    for (int k = 0; k < 64; ++k) {
        float4 w = *(const float4*)(W0 + (k << 8) + colb);
        const float* ar = &As[k][rowb];
#pragma unroll
        for (int r = 0; r < 16; ++r) fma4(acc[r], ar[r], w);
    }
    if (A1) {
#pragma unroll 4
        for (int k = 0; k < 64; ++k) {
            float4 w = *(const float4*)(W1 + (k << 8) + colb);
            const float* ar = &As[64 + k][rowb];
#pragma unroll
            for (int r = 0; r < 16; ++r) fma4(acc[r], ar[r], w);
        }
    }

    float4 bv = *(const float4*)(bias + colb);
#pragma unroll
    for (int r = 0; r < 16; ++r) {
        int gr = m0 + rowb + r;
        if (gr < n) {
            float4 o;
            o.x = acc[r].x + bv.x; o.y = acc[r].y + bv.y;
            o.z = acc[r].z + bv.z; o.w = acc[r].w + bv.w;
            if (do_relu) {
                o.x = fmaxf(o.x, 0.f); o.y = fmaxf(o.y, 0.f);
                o.z = fmaxf(o.z, 0.f); o.w = fmaxf(o.w, 0.f);
            }
            *(float4*)(C + (size_t)gr * ldc + colb) = o;
        }
    }
}

// Dual-output: C[m,0:64]=A@Wa, C[m,64:128]=A@Wb  (A: n x K, Wa/Wb: K x 64, ldc=128)
__global__ __launch_bounds__(128) void gemm_dual64(
    const float* __restrict__ A, int lda, int K,
    const float* __restrict__ Wa, const float* __restrict__ Wb,
    float* __restrict__ C, int n)
{
    __shared__ float As[64][68];
    const int m0 = blockIdx.x * 64;
    const int t = threadIdx.x;
    const int tn = t & 15, tm = t >> 4;
    const int colb = tn * 4, rowb = tm * 8;

    float4 aa[8], ab[8];
#pragma unroll
    for (int r = 0; r < 8; ++r) { aa[r] = make_float4(0.f,0.f,0.f,0.f); ab[r] = aa[r]; }

    for (int kc = 0; kc < K; kc += 64) {
        __syncthreads();
        for (int i = t; i < 64 * 16; i += 128) {
            int row = i >> 4, c4 = (i & 15) * 4;
            int gr = m0 + row;
            float4 v = make_float4(0.f, 0.f, 0.f, 0.f);
            if (gr < n) v = *(const float4*)(A + (size_t)gr * lda + kc + c4);
            As[c4 + 0][row] = v.x; As[c4 + 1][row] = v.y;
            As[c4 + 2][row] = v.z; As[c4 + 3][row] = v.w;
        }
        __syncthreads();
        const float* Wra = Wa + kc * 64;
        const float* Wrb = Wb + kc * 64;
#pragma unroll 4
        for (int k = 0; k < 64; ++k) {
            float4 wa = *(const float4*)(Wra + (k << 6) + colb);
            float4 wb = *(const float4*)(Wrb + (k << 6) + colb);
            const float* ar = &As[k][rowb];
#pragma unroll
            for (int r = 0; r < 8; ++r) { fma4(aa[r], ar[r], wa); fma4(ab[r], ar[r], wb); }
        }
    }

#pragma unroll
    for (int r = 0; r < 8; ++r) {
        int gr = m0 + rowb + r;
        if (gr < n) {
            *(float4*)(C + (size_t)gr * 128 + colb) = aa[r];
            *(float4*)(C + (size_t)gr * 128 + 64 + colb) = ab[r];
        }
    }
}

// C[m, 0:64] = A[m,0:K] @ W + bias
__global__ __launch_bounds__(128) void gemm_n64(
    const float* __restrict__ A, int lda, int K,
    const float* __restrict__ W, const float* __restrict__ bias,
    float* __restrict__ C, int ldc, int n)
{
    __shared__ float As[64][68];
    const int m0 = blockIdx.x * 64;
    const int t = threadIdx.x;
    const int tn = t & 15, tm = t >> 4;
    const int colb = tn * 4, rowb = tm * 8;

    float4 acc[8];
#pragma unroll
    for (int r = 0; r < 8; ++r) acc[r] = make_float4(0.f, 0.f, 0.f, 0.f);

    for (int kc = 0; kc < K; kc += 64) {
        __syncthreads();
        for (int i = t; i < 64 * 16; i += 128) {
            int row = i >> 4, c4 = (i & 15) * 4;
            int gr = m0 + row;
            float4 v = make_float4(0.f, 0.f, 0.f, 0.f);
            if (gr < n) v = *(const float4*)(A + (size_t)gr * lda + kc + c4);
            As[c4 + 0][row] = v.x; As[c4 + 1][row] = v.y;
            As[c4 + 2][row] = v.z; As[c4 + 3][row] = v.w;
        }
        __syncthreads();
        const float* Wb = W + kc * 64;
#pragma unroll 4
        for (int k = 0; k < 64; ++k) {
            float4 w = *(const float4*)(Wb + (k << 6) + colb);
            const float* ar = &As[k][rowb];
#pragma unroll
            for (int r = 0; r < 8; ++r) fma4(acc[r], ar[r], w);
        }
    }

    float4 bv = *(const float4*)(bias + colb);
#pragma unroll
    for (int r = 0; r < 8; ++r) {
        int gr = m0 + rowb + r;
        if (gr < n) {
            float4 o;
            o.x = acc[r].x + bv.x; o.y = acc[r].y + bv.y;
            o.z = acc[r].z + bv.z; o.w = acc[r].w + bv.w;
            *(float4*)(C + (size_t)gr * ldc + colb) = o;
        }
    }
}

extern "C" void kernel_launch(void* const* d_in, const int* in_sizes, int n_in,
                              void* d_out, int out_size, void* d_ws, size_t ws_size,
                              hipStream_t stream) {
    const float* x      = (const float*)d_in[0];
    const int*   ei     = (const int*)d_in[1];
    const float* W1     = (const float*)d_in[2];   // (8,64,256): W1[0] = first 16384
    const float* root1  = (const float*)d_in[3];
    const float* b1     = (const float*)d_in[4];
    const float* W2     = (const float*)d_in[5];   // (8,256,64): W2[0] = first 16384
    const float* root2  = (const float*)d_in[6];
    const float* b2     = (const float*)d_in[7];
    const float* dw1    = (const float*)d_in[8];
    const float* db1    = (const float*)d_in[9];
    const float* dw2    = (const float*)d_in[10];
    const float* db2    = (const float*)d_in[11];
    float* out = (float*)d_out;

    const int N = in_sizes[0] / 64;
    const int E = in_sizes[1] / 2;
    const int* srcv = ei;
    const int* dstv = ei + E;

    char* ws = (char*)d_ws;
    auto alloc = [&](size_t bytes) -> void* {
        void* p = (void*)ws;
        ws += (bytes + 255) & ~(size_t)255;
        return p;
    };
    int*   cnt    = (int*)alloc((size_t)N * 4);
    int*   cursor = (int*)alloc((size_t)N * 4);
    int*   offs   = (int*)alloc((size_t)(N + 1) * 4);
    int*   bsum   = (int*)alloc(1024);
    int*   total  = (int*)alloc(256);
    float* invd   = (float*)alloc((size_t)N * 4);
    int*   esrc   = (int*)alloc((size_t)E * 4);
    float* agg1   = (float*)alloc((size_t)N * 64 * 4);
    float* h      = (float*)alloc((size_t)N * 256 * 4);
    float* hwroot = (float*)alloc((size_t)N * 128 * 4);
    float* z      = agg1;   // agg1 dead after layer-1 GEMM
    float* h2     = h;      // h dead after gemm_dual64

    hipMemsetAsync(cnt, 0, (size_t)N * 4, stream);
    hipMemsetAsync(cursor, 0, (size_t)N * 4, stream);

    int eb = (E + THREADS - 1) / THREADS;
    int nb = (N + THREADS - 1) / THREADS;
    int sb = (N + 1023) / 1024;           // scan blocks (<=256)
    int gb = (N + 63) / 64;

    count_edges<<<eb, THREADS, 0, stream>>>(dstv, cnt, E);
    scan_block<<<sb, 256, 0, stream>>>(cnt, offs, bsum, N);
    scan_partials<<<1, 256, 0, stream>>>(bsum, total, sb);
    scan_add<<<nb, THREADS, 0, stream>>>(offs, bsum, total, N);
    fill_csr<<<eb, THREADS, 0, stream>>>(srcv, dstv, offs, cursor, esrc, E);
    inv_deg_kernel<<<nb, THREADS, 0, stream>>>(cnt, invd, N);

    // layer 1
    agg_mean_64u<<<(N + 3) / 4, THREADS, 0, stream>>>(x, esrc, offs, invd, agg1, N);
    gemm_n256<<<gb, 256, 0, stream>>>(agg1, 64, x, 64, W1, root1, b1, h, 256, N, 1);
    // layer 2: project-then-aggregate
    gemm_dual64<<<gb, 128, 0, stream>>>(h, 256, 256, W2, root2, hwroot, N);
    agg_z<<<(N + 3) / 4, THREADS, 0, stream>>>(hwroot, esrc, offs, invd, b2, z, N);
    // decoder
    gemm_n256<<<gb, 256, 0, stream>>>(z, 64, nullptr, 0, dw1, nullptr, db1, h2, 256, N, 1);
    gemm_n64<<<gb, 128, 0, stream>>>(h2, 256, 256, dw2, db2, out, 64, N);
}

// Round 4
// 464.961 us; speedup vs baseline: 2.3996x; 1.0544x over previous
//
#include <hip/hip_runtime.h>
#include <hip/hip_bf16.h>

// GraphAE: pseudo == 0  =>  spline basis c[:,k] = delta(k,0); only W[0] matters.
// Linearization: mean(h[src]) @ W2_0 == mean(h[src] @ W2_0)  -> project to 64-dim
// BEFORE the gather (4x less traffic, gather table L2/L3-resident).
// GEMM design (all 4): 64-row M-tiles, row-major LDS A staging (pad 68) with
// ds_write_b128 (2-way, free) and broadcast ds_read_b128 (row-interleaved thread
// mapping -> distinct banks per wave), k4-blocked inner loop, float4 W streams.

#define THREADS 256

__device__ __forceinline__ void fma4(float4& acc, float a, const float4& w) {
    acc.x += a * w.x; acc.y += a * w.y; acc.z += a * w.z; acc.w += a * w.w;
}

__global__ void count_edges(const int* __restrict__ dst, int* __restrict__ cnt, int E) {
    int e = blockIdx.x * blockDim.x + threadIdx.x;
    if (e < E) atomicAdd(&cnt[dst[e]], 1);
}

// ---- hierarchical exclusive scan: 1024 elems/block (256 thr x 4) ----
__global__ void scan_block(const int* __restrict__ cnt, int* __restrict__ offs,
                           int* __restrict__ bsum, int n) {
    __shared__ int tsum[256];
    int t = threadIdx.x;
    int base = blockIdx.x * 1024 + t * 4;
    int v0 = (base + 0 < n) ? cnt[base + 0] : 0;
    int v1 = (base + 1 < n) ? cnt[base + 1] : 0;
    int v2 = (base + 2 < n) ? cnt[base + 2] : 0;
    int v3 = (base + 3 < n) ? cnt[base + 3] : 0;
    int s = v0 + v1 + v2 + v3;
    tsum[t] = s;
    __syncthreads();
    for (int off = 1; off < 256; off <<= 1) {
        int xv = (t >= off) ? tsum[t - off] : 0;
        __syncthreads();
        tsum[t] += xv;
        __syncthreads();
    }
    int excl = tsum[t] - s;
    if (base + 0 < n) offs[base + 0] = excl;
    if (base + 1 < n) offs[base + 1] = excl + v0;
    if (base + 2 < n) offs[base + 2] = excl + v0 + v1;
    if (base + 3 < n) offs[base + 3] = excl + v0 + v1 + v2;
    if (t == 255) bsum[blockIdx.x] = tsum[255];
}

__global__ void scan_partials(int* __restrict__ bsum, int* __restrict__ total, int nb) {
    __shared__ int sm[256];
    int t = threadIdx.x;
    int v = (t < nb) ? bsum[t] : 0;
    sm[t] = v;
    __syncthreads();
    for (int off = 1; off < 256; off <<= 1) {
        int xv = (t >= off) ? sm[t - off] : 0;
        __syncthreads();
        sm[t] += xv;
        __syncthreads();
    }
    if (t < nb) bsum[t] = sm[t] - v;
    if (t == 255) *total = sm[255];
}

__global__ void scan_add(int* __restrict__ offs, const int* __restrict__ bsum,
                         const int* __restrict__ total, int n) {
    int i = blockIdx.x * blockDim.x + threadIdx.x;
    if (i < n) offs[i] += bsum[i >> 10];
    if (i == 0) offs[n] = *total;
}

__global__ void fill_csr(const int* __restrict__ src, const int* __restrict__ dst,
                         const int* __restrict__ offs, int* __restrict__ cursor,
                         int* __restrict__ esrc, int E) {
    int e = blockIdx.x * blockDim.x + threadIdx.x;
    if (e < E) {
        int d = dst[e];
        int p = atomicAdd(&cursor[d], 1);
        esrc[offs[d] + p] = src[e];
    }
}

__global__ void inv_deg_kernel(const int* __restrict__ cnt, float* __restrict__ invd, int n) {
    int i = blockIdx.x * blockDim.x + threadIdx.x;
    if (i < n) invd[i] = 1.0f / (float)max(cnt[i], 1);
}

// mean-aggregate 64-wide rows (x): 4 nodes/block, one wave each, 4x edge unroll
__global__ void agg_mean_64u(const float* __restrict__ x, const int* __restrict__ esrc,
                             const int* __restrict__ offs, const float* __restrict__ invd,
                             float* __restrict__ agg, int n) {
    int node = blockIdx.x * 4 + (threadIdx.x >> 6);
    int l = threadIdx.x & 63;
    if (node >= n) return;
    int s = offs[node], e = offs[node + 1];
    float a0 = 0.f, a1 = 0.f, a2 = 0.f, a3 = 0.f;
    int j = s;
    for (; j + 4 <= e; j += 4) {
        int i0 = esrc[j], i1 = esrc[j + 1], i2 = esrc[j + 2], i3 = esrc[j + 3];
        a0 += x[(size_t)i0 * 64 + l];
        a1 += x[(size_t)i1 * 64 + l];
        a2 += x[(size_t)i2 * 64 + l];
        a3 += x[(size_t)i3 * 64 + l];
    }
    for (; j < e; ++j) a0 += x[(size_t)esrc[j] * 64 + l];
    agg[(size_t)node * 64 + l] = (a0 + a1 + a2 + a3) * invd[node];
}

// z = mean(hw[src]) + hroot + b2 ; hwroot is N x 128 (cols 0:64 hw, 64:128 hroot)
__global__ void agg_z(const float* __restrict__ hwroot, const int* __restrict__ esrc,
                      const int* __restrict__ offs, const float* __restrict__ invd,
                      const float* __restrict__ b2, float* __restrict__ z, int n) {
    int node = blockIdx.x * 4 + (threadIdx.x >> 6);
    int l = threadIdx.x & 63;
    if (node >= n) return;
    int s = offs[node], e = offs[node + 1];
    float a0 = 0.f, a1 = 0.f, a2 = 0.f, a3 = 0.f;
    int j = s;
    for (; j + 4 <= e; j += 4) {
        int i0 = esrc[j], i1 = esrc[j + 1], i2 = esrc[j + 2], i3 = esrc[j + 3];
        a0 += hwroot[(size_t)i0 * 128 + l];
        a1 += hwroot[(size_t)i1 * 128 + l];
        a2 += hwroot[(size_t)i2 * 128 + l];
        a3 += hwroot[(size_t)i3 * 128 + l];
    }
    for (; j < e; ++j) a0 += hwroot[(size_t)esrc[j] * 128 + l];
    z[(size_t)node * 64 + l] =
        (a0 + a1 + a2 + a3) * invd[node] + hwroot[(size_t)node * 128 + 64 + l] + b2[l];
}

// layer 1: C = relu(A0@W0 + A1@W1 + b), A0/A1: n x 64 (ld 64), W: 64 x 256, C: n x 256
// 256 thr: tc = t&63 (4 cols), tr = t>>6; rows = tr + 4*r, r in [0,16)
__global__ __launch_bounds__(256) void gemm1_n256(
    const float* __restrict__ A0, const float* __restrict__ A1,
    const float* __restrict__ W0, const float* __restrict__ W1,
    const float* __restrict__ bias, float* __restrict__ C, int n)
{
    __shared__ float As0[64][68];
    __shared__ float As1[64][68];
    const int m0 = blockIdx.x * 64;
    const int t = threadIdx.x;

    for (int i = t; i < 1024; i += 256) {
        int row = i >> 4, c4 = (i & 15) << 2;
        int gr = m0 + row;
        float4 v0 = make_float4(0.f, 0.f, 0.f, 0.f), v1 = v0;
        if (gr < n) {
            v0 = *(const float4*)(A0 + (size_t)gr * 64 + c4);
            v1 = *(const float4*)(A1 + (size_t)gr * 64 + c4);
        }
        *(float4*)&As0[row][c4] = v0;
        *(float4*)&As1[row][c4] = v1;
    }
    __syncthreads();

    const int tc = t & 63, tr = t >> 6;
    const int colb = tc * 4;

    float4 acc[16];
#pragma unroll
    for (int r = 0; r < 16; ++r) acc[r] = make_float4(0.f, 0.f, 0.f, 0.f);

#pragma unroll 2
    for (int k4 = 0; k4 < 16; ++k4) {
        int k = k4 * 4;
        float4 w0 = *(const float4*)(W0 + (k + 0) * 256 + colb);
        float4 w1 = *(const float4*)(W0 + (k + 1) * 256 + colb);
        float4 w2 = *(const float4*)(W0 + (k + 2) * 256 + colb);
        float4 w3 = *(const float4*)(W0 + (k + 3) * 256 + colb);
#pragma unroll
        for (int r = 0; r < 16; ++r) {
            float4 a = *(const float4*)&As0[tr + 4 * r][k];
            fma4(acc[r], a.x, w0); fma4(acc[r], a.y, w1);
            fma4(acc[r], a.z, w2); fma4(acc[r], a.w, w3);
        }
    }
#pragma unroll 2
    for (int k4 = 0; k4 < 16; ++k4) {
        int k = k4 * 4;
        float4 w0 = *(const float4*)(W1 + (k + 0) * 256 + colb);
        float4 w1 = *(const float4*)(W1 + (k + 1) * 256 + colb);
        float4 w2 = *(const float4*)(W1 + (k + 2) * 256 + colb);
        float4 w3 = *(const float4*)(W1 + (k + 3) * 256 + colb);
#pragma unroll
        for (int r = 0; r < 16; ++r) {
            float4 a = *(const float4*)&As1[tr + 4 * r][k];
            fma4(acc[r], a.x, w0); fma4(acc[r], a.y, w1);
            fma4(acc[r], a.z, w2); fma4(acc[r], a.w, w3);
        }
    }

    float4 bv = *(const float4*)(bias + colb);
#pragma unroll
    for (int r = 0; r < 16; ++r) {
        int gr = m0 + tr + 4 * r;
        if (gr < n) {
            float4 o;
            o.x = fmaxf(acc[r].x + bv.x, 0.f); o.y = fmaxf(acc[r].y + bv.y, 0.f);
            o.z = fmaxf(acc[r].z + bv.z, 0.f); o.w = fmaxf(acc[r].w + bv.w, 0.f);
            *(float4*)(C + (size_t)gr * 256 + colb) = o;
        }
    }
}

// dual 64-col: C[m,0:64]=A@Wa, C[m,64:128]=A@Wb; A: n x 256, Wa/Wb: 256 x 64, C ld 128
// 256 thr: tc = t&15 (4 cols), tr = t>>4; rows = tr + 16*r, r in [0,4)
__global__ __launch_bounds__(256) void gemm_dual64(
    const float* __restrict__ A, const float* __restrict__ Wa,
    const float* __restrict__ Wb, float* __restrict__ C, int n)
{
    __shared__ float As[64][68];
    const int m0 = blockIdx.x * 64;
    const int t = threadIdx.x;
    const int tc = t & 15, tr = t >> 4;
    const int colb = tc * 4;

    float4 aa[4], ab[4];
#pragma unroll
    for (int r = 0; r < 4; ++r) { aa[r] = make_float4(0.f, 0.f, 0.f, 0.f); ab[r] = aa[r]; }

    for (int kc = 0; kc < 256; kc += 64) {
        __syncthreads();
        for (int i = t; i < 1024; i += 256) {
            int row = i >> 4, c4 = (i & 15) << 2;
            int gr = m0 + row;
            float4 v = make_float4(0.f, 0.f, 0.f, 0.f);
            if (gr < n) v = *(const float4*)(A + (size_t)gr * 256 + kc + c4);
            *(float4*)&As[row][c4] = v;
        }
        __syncthreads();
        const float* Wak = Wa + kc * 64;
        const float* Wbk = Wb + kc * 64;
#pragma unroll 2
        for (int k4 = 0; k4 < 16; ++k4) {
            int k = k4 * 4;
            float4 wa0 = *(const float4*)(Wak + (k + 0) * 64 + colb);
            float4 wa1 = *(const float4*)(Wak + (k + 1) * 64 + colb);
            float4 wa2 = *(const float4*)(Wak + (k + 2) * 64 + colb);
            float4 wa3 = *(const float4*)(Wak + (k + 3) * 64 + colb);
            float4 wb0 = *(const float4*)(Wbk + (k + 0) * 64 + colb);
            float4 wb1 = *(const float4*)(Wbk + (k + 1) * 64 + colb);
            float4 wb2 = *(const float4*)(Wbk + (k + 2) * 64 + colb);
            float4 wb3 = *(const float4*)(Wbk + (k + 3) * 64 + colb);
#pragma unroll
            for (int r = 0; r < 4; ++r) {
                float4 a = *(const float4*)&As[tr + 16 * r][k];
                fma4(aa[r], a.x, wa0); fma4(aa[r], a.y, wa1);
                fma4(aa[r], a.z, wa2); fma4(aa[r], a.w, wa3);
                fma4(ab[r], a.x, wb0); fma4(ab[r], a.y, wb1);
                fma4(ab[r], a.z, wb2); fma4(ab[r], a.w, wb3);
            }
        }
    }

#pragma unroll
    for (int r = 0; r < 4; ++r) {
        int gr = m0 + tr + 16 * r;
        if (gr < n) {
            *(float4*)(C + (size_t)gr * 128 + colb) = aa[r];
            *(float4*)(C + (size_t)gr * 128 + 64 + colb) = ab[r];
        }
    }
}

// decoder 1: C = relu(A@W + b), A: n x 64 (ld 64), W: 64 x 256, C: n x 256
__global__ __launch_bounds__(256) void dec1_n256(
    const float* __restrict__ A, const float* __restrict__ W,
    const float* __restrict__ bias, float* __restrict__ C, int n)
{
    __shared__ float As[64][68];
    const int m0 = blockIdx.x * 64;
    const int t = threadIdx.x;

    for (int i = t; i < 1024; i += 256) {
        int row = i >> 4, c4 = (i & 15) << 2;
        int gr = m0 + row;
        float4 v = make_float4(0.f, 0.f, 0.f, 0.f);
        if (gr < n) v = *(const float4*)(A + (size_t)gr * 64 + c4);
        *(float4*)&As[row][c4] = v;
    }
    __syncthreads();

    const int tc = t & 63, tr = t >> 6;
    const int colb = tc * 4;

    float4 acc[16];
#pragma unroll
    for (int r = 0; r < 16; ++r) acc[r] = make_float4(0.f, 0.f, 0.f, 0.f);

#pragma unroll 2
    for (int k4 = 0; k4 < 16; ++k4) {
        int k = k4 * 4;
        float4 w0 = *(const float4*)(W + (k + 0) * 256 + colb);
        float4 w1 = *(const float4*)(W + (k + 1) * 256 + colb);
        float4 w2 = *(const float4*)(W + (k + 2) * 256 + colb);
        float4 w3 = *(const float4*)(W + (k + 3) * 256 + colb);
#pragma unroll
        for (int r = 0; r < 16; ++r) {
            float4 a = *(const float4*)&As[tr + 4 * r][k];
            fma4(acc[r], a.x, w0); fma4(acc[r], a.y, w1);
            fma4(acc[r], a.z, w2); fma4(acc[r], a.w, w3);
        }
    }

    float4 bv = *(const float4*)(bias + colb);
#pragma unroll
    for (int r = 0; r < 16; ++r) {
        int gr = m0 + tr + 4 * r;
        if (gr < n) {
            float4 o;
            o.x = fmaxf(acc[r].x + bv.x, 0.f); o.y = fmaxf(acc[r].y + bv.y, 0.f);
            o.z = fmaxf(acc[r].z + bv.z, 0.f); o.w = fmaxf(acc[r].w + bv.w, 0.f);
            *(float4*)(C + (size_t)gr * 256 + colb) = o;
        }
    }
}

// decoder 2: C = A@W + b, A: n x 256, W: 256 x 64, C: n x 64
// 128 thr: tc = t&15 (4 cols), tr = t>>4 in [0,8); rows = tr + 8*r, r in [0,8)
__global__ __launch_bounds__(128) void dec2_n64(
    const float* __restrict__ A, const float* __restrict__ W,
    const float* __restrict__ bias, float* __restrict__ C, int n)
{
    __shared__ float As[64][68];
    const int m0 = blockIdx.x * 64;
    const int t = threadIdx.x;
    const int tc = t & 15, tr = t >> 4;
    const int colb = tc * 4;

    float4 acc[8];
#pragma unroll
    for (int r = 0; r < 8; ++r) acc[r] = make_float4(0.f, 0.f, 0.f, 0.f);

    for (int kc = 0; kc < 256; kc += 64) {
        __syncthreads();
        for (int i = t; i < 1024; i += 128) {
            int row = i >> 4, c4 = (i & 15) << 2;
            int gr = m0 + row;
            float4 v = make_float4(0.f, 0.f, 0.f, 0.f);
            if (gr < n) v = *(const float4*)(A + (size_t)gr * 256 + kc + c4);
            *(float4*)&As[row][c4] = v;
        }
        __syncthreads();
        const float* Wk = W + kc * 64;
#pragma unroll 2
        for (int k4 = 0; k4 < 16; ++k4) {
            int k = k4 * 4;
            float4 w0 = *(const float4*)(Wk + (k + 0) * 64 + colb);
            float4 w1 = *(const float4*)(Wk + (k + 1) * 64 + colb);
            float4 w2 = *(const float4*)(Wk + (k + 2) * 64 + colb);
            float4 w3 = *(const float4*)(Wk + (k + 3) * 64 + colb);
#pragma unroll
            for (int r = 0; r < 8; ++r) {
                float4 a = *(const float4*)&As[tr + 8 * r][k];
                fma4(acc[r], a.x, w0); fma4(acc[r], a.y, w1);
                fma4(acc[r], a.z, w2); fma4(acc[r], a.w, w3);
            }
        }
    }

    float4 bv = *(const float4*)(bias + colb);
#pragma unroll
    for (int r = 0; r < 8; ++r) {
        int gr = m0 + tr + 8 * r;
        if (gr < n) {
            float4 o;
            o.x = acc[r].x + bv.x; o.y = acc[r].y + bv.y;
            o.z = acc[r].z + bv.z; o.w = acc[r].w + bv.w;
            *(float4*)(C + (size_t)gr * 64 + colb) = o;
        }
    }
}

extern "C" void kernel_launch(void* const* d_in, const int* in_sizes, int n_in,
                              void* d_out, int out_size, void* d_ws, size_t ws_size,
                              hipStream_t stream) {
    const float* x      = (const float*)d_in[0];
    const int*   ei     = (const int*)d_in[1];
    const float* W1     = (const float*)d_in[2];   // (8,64,256): W1[0] = first 16384
    const float* root1  = (const float*)d_in[3];
    const float* b1     = (const float*)d_in[4];
    const float* W2     = (const float*)d_in[5];   // (8,256,64): W2[0] = first 16384
    const float* root2  = (const float*)d_in[6];
    const float* b2     = (const float*)d_in[7];
    const float* dw1    = (const float*)d_in[8];
    const float* db1    = (const float*)d_in[9];
    const float* dw2    = (const float*)d_in[10];
    const float* db2    = (const float*)d_in[11];
    float* out = (float*)d_out;

    const int N = in_sizes[0] / 64;
    const int E = in_sizes[1] / 2;
    const int* srcv = ei;
    const int* dstv = ei + E;

    char* ws = (char*)d_ws;
    auto alloc = [&](size_t bytes) -> void* {
        void* p = (void*)ws;
        ws += (bytes + 255) & ~(size_t)255;
        return p;
    };
    int*   cnt    = (int*)alloc((size_t)N * 4);
    int*   cursor = (int*)alloc((size_t)N * 4);
    int*   offs   = (int*)alloc((size_t)(N + 1) * 4);
    int*   bsum   = (int*)alloc(1024);
    int*   total  = (int*)alloc(256);
    float* invd   = (float*)alloc((size_t)N * 4);
    int*   esrc   = (int*)alloc((size_t)E * 4);
    float* agg1   = (float*)alloc((size_t)N * 64 * 4);
    float* h      = (float*)alloc((size_t)N * 256 * 4);
    float* hwroot = (float*)alloc((size_t)N * 128 * 4);
    float* z      = agg1;   // agg1 dead after layer-1 GEMM
    float* h2     = h;      // h dead after gemm_dual64

    hipMemsetAsync(cnt, 0, (size_t)N * 4, stream);
    hipMemsetAsync(cursor, 0, (size_t)N * 4, stream);

    int eb = (E + THREADS - 1) / THREADS;
    int nb = (N + THREADS - 1) / THREADS;
    int sb = (N + 1023) / 1024;
    int gb = (N + 63) / 64;

    count_edges<<<eb, THREADS, 0, stream>>>(dstv, cnt, E);
    scan_block<<<sb, 256, 0, stream>>>(cnt, offs, bsum, N);
    scan_partials<<<1, 256, 0, stream>>>(bsum, total, sb);
    scan_add<<<nb, THREADS, 0, stream>>>(offs, bsum, total, N);
    fill_csr<<<eb, THREADS, 0, stream>>>(srcv, dstv, offs, cursor, esrc, E);
    inv_deg_kernel<<<nb, THREADS, 0, stream>>>(cnt, invd, N);

    // layer 1
    agg_mean_64u<<<(N + 3) / 4, THREADS, 0, stream>>>(x, esrc, offs, invd, agg1, N);
    gemm1_n256<<<gb, 256, 0, stream>>>(agg1, x, W1, root1, b1, h, N);
    // layer 2: project-then-aggregate
    gemm_dual64<<<gb, 256, 0, stream>>>(h, W2, root2, hwroot, N);
    agg_z<<<(N + 3) / 4, THREADS, 0, stream>>>(hwroot, esrc, offs, invd, b2, z, N);
    // decoder
    dec1_n256<<<gb, 256, 0, stream>>>(z, dw1, db1, h2, N);
    dec2_n64<<<gb, 128, 0, stream>>>(h2, dw2, db2, out, N);
}

// Round 5
// 344.758 us; speedup vs baseline: 3.2362x; 1.3487x over previous
//
#include <hip/hip_runtime.h>
#include <hip/hip_bf16.h>

// GraphAE: pseudo == 0 => only W[0] of the 8 spline matrices matters.
// Linearization: mean(h[src])@W2_0 == mean(h[src]@W2_0) -> project before gather.
// This round: all 4 GEMMs on bf16 MFMA (v_mfma_f32_16x16x32_bf16), weights
// pre-packed into B-fragment lane layout, activations stored bf16 (halves
// gather traffic). No LDS in GEMMs: A frags loaded 16B/lane from row-major
// bf16, B frags 16B/lane coalesced from packed layout.
//
// Verified MFMA layouts (guide §3): A[m=lane&15][k=(lane>>4)*8+j],
// B[k=(lane>>4)*8+j][n=lane&15], D[row=(lane>>4)*4+r][col=lane&15].

#define THREADS 256

typedef __attribute__((ext_vector_type(8))) short bf16x8;   // 8 bf16 = 4 VGPRs
typedef __attribute__((ext_vector_type(4))) float f32x4;    // acc

__device__ __forceinline__ float bf2f(unsigned short u) {
    unsigned v = ((unsigned)u) << 16;
    return __builtin_bit_cast(float, v);
}
__device__ __forceinline__ unsigned short f2bf(float f) {
    __hip_bfloat16 h = __float2bfloat16(f);   // RNE
    return __builtin_bit_cast(unsigned short, h);
}

// ---------------- CSR build ----------------
__global__ void count_edges(const int* __restrict__ dst, int* __restrict__ cnt, int E) {
    int e = blockIdx.x * blockDim.x + threadIdx.x;
    if (e < E) atomicAdd(&cnt[dst[e]], 1);
}

__global__ void scan_block(const int* __restrict__ cnt, int* __restrict__ offs,
                           int* __restrict__ bsum, int n) {
    __shared__ int tsum[256];
    int t = threadIdx.x;
    int base = blockIdx.x * 1024 + t * 4;
    int v0 = (base + 0 < n) ? cnt[base + 0] : 0;
    int v1 = (base + 1 < n) ? cnt[base + 1] : 0;
    int v2 = (base + 2 < n) ? cnt[base + 2] : 0;
    int v3 = (base + 3 < n) ? cnt[base + 3] : 0;
    int s = v0 + v1 + v2 + v3;
    tsum[t] = s;
    __syncthreads();
    for (int off = 1; off < 256; off <<= 1) {
        int xv = (t >= off) ? tsum[t - off] : 0;
        __syncthreads();
        tsum[t] += xv;
        __syncthreads();
    }
    int excl = tsum[t] - s;
    if (base + 0 < n) offs[base + 0] = excl;
    if (base + 1 < n) offs[base + 1] = excl + v0;
    if (base + 2 < n) offs[base + 2] = excl + v0 + v1;
    if (base + 3 < n) offs[base + 3] = excl + v0 + v1 + v2;
    if (t == 255) bsum[blockIdx.x] = tsum[255];
}

__global__ void scan_partials(int* __restrict__ bsum, int* __restrict__ total, int nb) {
    __shared__ int sm[256];
    int t = threadIdx.x;
    int v = (t < nb) ? bsum[t] : 0;
    sm[t] = v;
    __syncthreads();
    for (int off = 1; off < 256; off <<= 1) {
        int xv = (t >= off) ? sm[t - off] : 0;
        __syncthreads();
        sm[t] += xv;
        __syncthreads();
    }
    if (t < nb) bsum[t] = sm[t] - v;
    if (t == 255) *total = sm[255];
}

__global__ void scan_add(int* __restrict__ offs, const int* __restrict__ bsum,
                         const int* __restrict__ total, int n) {
    int i = blockIdx.x * blockDim.x + threadIdx.x;
    if (i < n) offs[i] += bsum[i >> 10];
    if (i == 0) offs[n] = *total;
}

__global__ void fill_csr(const int* __restrict__ src, const int* __restrict__ dst,
                         const int* __restrict__ offs, int* __restrict__ cursor,
                         int* __restrict__ esrc, int E) {
    int e = blockIdx.x * blockDim.x + threadIdx.x;
    if (e < E) {
        int d = dst[e];
        int p = atomicAdd(&cursor[d], 1);
        esrc[offs[d] + p] = src[e];
    }
}

__global__ void inv_deg_kernel(const int* __restrict__ cnt, float* __restrict__ invd, int n) {
    int i = blockIdx.x * blockDim.x + threadIdx.x;
    if (i < n) invd[i] = 1.0f / (float)max(cnt[i], 1);
}

// ---------------- weight pack + x convert ----------------
// Pack fp32 W (eff. K x NOUT) into MFMA B-frag layout bf16:
// dst[(((s*NB + j)*64 + lane)*8 + i] = W[s*32 + (lane>>4)*8 + i][j*16 + (lane&15)]
__device__ __forceinline__ void pack_one(unsigned short* dst,
                                         const float* W0, const float* W1,
                                         int NB, int ksplit, int colsplit,
                                         int ld0, int ld1, int t) {
    int i = t & 7, lane = (t >> 3) & 63, rest = t >> 9;
    int j = rest % NB, s = rest / NB;
    int k = s * 32 + ((lane >> 4) << 3) + i;
    int c = (j << 4) + (lane & 15);
    float v;
    if (c >= colsplit)    v = W1[(size_t)k * ld1 + (c - colsplit)];
    else if (k >= ksplit) v = W1[(size_t)(k - ksplit) * ld1 + c];
    else                  v = W0[(size_t)k * ld0 + c];
    dst[t] = f2bf(v);
}

#define BIG (1 << 30)

__global__ void prep_kernel(const float* __restrict__ W1g, const float* __restrict__ root1,
                            const float* __restrict__ W2g, const float* __restrict__ root2,
                            const float* __restrict__ dw1, const float* __restrict__ dw2,
                            const float* __restrict__ x,
                            unsigned short* __restrict__ Pb1,   // 128x256
                            unsigned short* __restrict__ Pb2,   // 256x128
                            unsigned short* __restrict__ Pd1,   // 64x256
                            unsigned short* __restrict__ Pd2,   // 256x64
                            unsigned short* __restrict__ ab1,   // N x 128, x -> cols 64:128
                            int n) {
    int t = blockIdx.x * blockDim.x + threadIdx.x;
    if (t < 32768) {
        pack_one(Pb1, W1g, root1, 16, 64, BIG, 256, 256, t);
    } else if (t < 65536) {
        pack_one(Pb2, W2g, root2, 8, BIG, 64, 64, 64, t - 32768);
    } else if (t < 81920) {
        pack_one(Pd1, dw1, dw1, 16, BIG, BIG, 256, 256, t - 65536);
    } else if (t < 98304) {
        pack_one(Pd2, dw2, dw2, 4, BIG, BIG, 64, 64, t - 81920);
    } else {
        int u = t - 98304;
        if (u < n * 64) {
            int row = u >> 6, col = u & 63;
            ab1[(size_t)row * 128 + 64 + col] = f2bf(x[(size_t)row * 64 + col]);
        }
    }
}

// ---------------- gathers (bf16 tables, fp32 accumulate) ----------------
// agg1 = mean(x[src]) : reads ab1 cols 64:128, writes ab1 cols 0:64
__global__ void agg_x_bf16(unsigned short* __restrict__ ab1, const int* __restrict__ esrc,
                           const int* __restrict__ offs, const float* __restrict__ invd,
                           int n) {
    int node = blockIdx.x * 4 + (threadIdx.x >> 6);
    int l = threadIdx.x & 63;
    if (node >= n) return;
    int s = offs[node], e = offs[node + 1];
    float a0 = 0.f, a1 = 0.f, a2 = 0.f, a3 = 0.f;
    int j = s;
    for (; j + 4 <= e; j += 4) {
        int i0 = esrc[j], i1 = esrc[j + 1], i2 = esrc[j + 2], i3 = esrc[j + 3];
        a0 += bf2f(ab1[(size_t)i0 * 128 + 64 + l]);
        a1 += bf2f(ab1[(size_t)i1 * 128 + 64 + l]);
        a2 += bf2f(ab1[(size_t)i2 * 128 + 64 + l]);
        a3 += bf2f(ab1[(size_t)i3 * 128 + 64 + l]);
    }
    for (; j < e; ++j) a0 += bf2f(ab1[(size_t)esrc[j] * 128 + 64 + l]);
    ab1[(size_t)node * 128 + l] = f2bf((a0 + a1 + a2 + a3) * invd[node]);
}

// z = mean(hw[src]) + hroot + b2 ; hwroot N x 128 bf16 (0:64 hw, 64:128 hroot)
__global__ void agg_z_bf16(const unsigned short* __restrict__ hwroot,
                           const int* __restrict__ esrc, const int* __restrict__ offs,
                           const float* __restrict__ invd, const float* __restrict__ b2,
                           unsigned short* __restrict__ z, int n) {
    int node = blockIdx.x * 4 + (threadIdx.x >> 6);
    int l = threadIdx.x & 63;
    if (node >= n) return;
    int s = offs[node], e = offs[node + 1];
    float a0 = 0.f, a1 = 0.f, a2 = 0.f, a3 = 0.f;
    int j = s;
    for (; j + 4 <= e; j += 4) {
        int i0 = esrc[j], i1 = esrc[j + 1], i2 = esrc[j + 2], i3 = esrc[j + 3];
        a0 += bf2f(hwroot[(size_t)i0 * 128 + l]);
        a1 += bf2f(hwroot[(size_t)i1 * 128 + l]);
        a2 += bf2f(hwroot[(size_t)i2 * 128 + l]);
        a3 += bf2f(hwroot[(size_t)i3 * 128 + l]);
    }
    for (; j < e; ++j) a0 += bf2f(hwroot[(size_t)esrc[j] * 128 + l]);
    float v = (a0 + a1 + a2 + a3) * invd[node]
            + bf2f(hwroot[(size_t)node * 128 + 64 + l]) + b2[l];
    z[(size_t)node * 64 + l] = f2bf(v);
}

// ---------------- MFMA GEMM: C = act(A @ W + bias) ----------------
// A: n x K bf16 row-major (padded rows beyond n are readable).
// Bp: packed per pack_one. 256 threads = 4 waves; M-tile 64 (4 m-blocks),
// wave w covers n-blocks [w*NB/4, (w+1)*NB/4).
template <int K, int NOUT, bool RELU, bool OUT_BF16>
__global__ __launch_bounds__(256) void mfma_gemm(
    const unsigned short* __restrict__ A,
    const unsigned short* __restrict__ Bp,
    const float* __restrict__ bias,
    void* __restrict__ Cv, int n)
{
    constexpr int NB = NOUT / 16;
    constexpr int NBW = NB / 4;
    constexpr int KS = K / 32;
    const int m0 = blockIdx.x * 64;
    const int lane = threadIdx.x & 63;
    const int w = threadIdx.x >> 6;
    const int quad = lane >> 4;
    const int l16 = lane & 15;

    f32x4 acc[4][NBW] = {};

    const unsigned short* Arow = A + (size_t)(m0 + l16) * K + quad * 8;

    for (int s = 0; s < KS; ++s) {
        bf16x8 a[4];
#pragma unroll
        for (int mb = 0; mb < 4; ++mb)
            a[mb] = *(const bf16x8*)(Arow + (size_t)mb * 16 * K + s * 32);
#pragma unroll
        for (int jn = 0; jn < NBW; ++jn) {
            int j = w * NBW + jn;
            bf16x8 b = *(const bf16x8*)(Bp + ((size_t)(s * NB + j) * 64 + lane) * 8);
#pragma unroll
            for (int mb = 0; mb < 4; ++mb)
                acc[mb][jn] = __builtin_amdgcn_mfma_f32_16x16x32_bf16(a[mb], b, acc[mb][jn], 0, 0, 0);
        }
    }

#pragma unroll
    for (int jn = 0; jn < NBW; ++jn) {
        int col = (w * NBW + jn) * 16 + l16;
        float bv = bias ? bias[col] : 0.f;
#pragma unroll
        for (int mb = 0; mb < 4; ++mb) {
#pragma unroll
            for (int r = 0; r < 4; ++r) {
                int row = m0 + mb * 16 + quad * 4 + r;
                if (row < n) {
                    float v = acc[mb][jn][r] + bv;
                    if (RELU) v = fmaxf(v, 0.f);
                    if (OUT_BF16)
                        ((unsigned short*)Cv)[(size_t)row * NOUT + col] = f2bf(v);
                    else
                        ((float*)Cv)[(size_t)row * NOUT + col] = v;
                }
            }
        }
    }
}

extern "C" void kernel_launch(void* const* d_in, const int* in_sizes, int n_in,
                              void* d_out, int out_size, void* d_ws, size_t ws_size,
                              hipStream_t stream) {
    const float* x      = (const float*)d_in[0];
    const int*   ei     = (const int*)d_in[1];
    const float* W1g    = (const float*)d_in[2];   // (8,64,256): [0] = first 16384
    const float* root1  = (const float*)d_in[3];
    const float* b1     = (const float*)d_in[4];
    const float* W2g    = (const float*)d_in[5];   // (8,256,64): [0] = first 16384
    const float* root2  = (const float*)d_in[6];
    const float* b2     = (const float*)d_in[7];
    const float* dw1    = (const float*)d_in[8];
    const float* db1    = (const float*)d_in[9];
    const float* dw2    = (const float*)d_in[10];
    const float* db2    = (const float*)d_in[11];
    float* out = (float*)d_out;

    const int N = in_sizes[0] / 64;
    const int E = in_sizes[1] / 2;
    const int Npad = N + 64;                      // pad rows for OOB A-frag reads
    const int* srcv = ei;
    const int* dstv = ei + E;

    char* ws = (char*)d_ws;
    auto alloc = [&](size_t bytes) -> void* {
        void* p = (void*)ws;
        ws += (bytes + 255) & ~(size_t)255;
        return p;
    };
    int*   cnt    = (int*)alloc((size_t)N * 4);
    int*   cursor = (int*)alloc((size_t)N * 4);
    int*   offs   = (int*)alloc((size_t)(N + 1) * 4);
    int*   bsum   = (int*)alloc(1024);
    int*   total  = (int*)alloc(256);
    float* invd   = (float*)alloc((size_t)N * 4);
    int*   esrc   = (int*)alloc((size_t)E * 4);
    unsigned short* Pb1 = (unsigned short*)alloc(32768 * 2);
    unsigned short* Pb2 = (unsigned short*)alloc(32768 * 2);
    unsigned short* Pd1 = (unsigned short*)alloc(16384 * 2);
    unsigned short* Pd2 = (unsigned short*)alloc(16384 * 2);
    unsigned short* ab1    = (unsigned short*)alloc((size_t)Npad * 128 * 2);  // [agg1 | xb]
    unsigned short* h      = (unsigned short*)alloc((size_t)Npad * 256 * 2);
    unsigned short* hwroot = (unsigned short*)alloc((size_t)Npad * 128 * 2);
    unsigned short* z      = (unsigned short*)alloc((size_t)Npad * 64 * 2);
    unsigned short* h2     = h;   // h dead after dual GEMM

    hipMemsetAsync(cnt, 0, (size_t)N * 4, stream);
    hipMemsetAsync(cursor, 0, (size_t)N * 4, stream);

    int eb = (E + THREADS - 1) / THREADS;
    int nb = (N + THREADS - 1) / THREADS;
    int sb = (N + 1023) / 1024;
    int gb = (N + 63) / 64;
    int pb = (98304 + N * 64 + THREADS - 1) / THREADS;

    // weight pack + x->bf16 (independent of CSR chain)
    prep_kernel<<<pb, THREADS, 0, stream>>>(W1g, root1, W2g, root2, dw1, dw2, x,
                                            Pb1, Pb2, Pd1, Pd2, ab1, N);
    // CSR
    count_edges<<<eb, THREADS, 0, stream>>>(dstv, cnt, E);
    scan_block<<<sb, 256, 0, stream>>>(cnt, offs, bsum, N);
    scan_partials<<<1, 256, 0, stream>>>(bsum, total, sb);
    scan_add<<<nb, THREADS, 0, stream>>>(offs, bsum, total, N);
    fill_csr<<<eb, THREADS, 0, stream>>>(srcv, dstv, offs, cursor, esrc, E);
    inv_deg_kernel<<<nb, THREADS, 0, stream>>>(cnt, invd, N);

    // layer 1: agg + fused GEMM  h = relu([agg1|x] @ [W1;root1] + b1)
    agg_x_bf16<<<(N + 3) / 4, THREADS, 0, stream>>>(ab1, esrc, offs, invd, N);
    mfma_gemm<128, 256, true, true><<<gb, 256, 0, stream>>>(ab1, Pb1, b1, h, N);
    // layer 2: project-then-aggregate
    mfma_gemm<256, 128, false, true><<<gb, 256, 0, stream>>>(h, Pb2, nullptr, hwroot, N);
    agg_z_bf16<<<(N + 3) / 4, THREADS, 0, stream>>>(hwroot, esrc, offs, invd, b2, z, N);
    // decoder
    mfma_gemm<64, 256, true, true><<<gb, 256, 0, stream>>>(z, Pd1, db1, h2, N);
    mfma_gemm<256, 64, false, false><<<gb, 256, 0, stream>>>(h2, Pd2, db2, out, N);
}

// Round 6
// 259.413 us; speedup vs baseline: 4.3009x; 1.3290x over previous
//
#include <hip/hip_runtime.h>
#include <hip/hip_bf16.h>

// GraphAE: pseudo == 0 => only W[0] of the 8 spline matrices matters.
// Linearization: mean(h[src])@W2_0 == mean(h[src]@W2_0) -> project before gather.
// Round 6:
//  - bucketed two-pass CSR fill (kills the 16x write amplification of the
//    random 4B scatter: pass A partitions edges into 256-node buckets with
//    LDS histograms, pass B does bucket-local ordering in LDS + coalesced write)
//  - fused GEMM pairs: [L1 GEMM -> LDS h-tile -> L2 projection] and
//    [dec1 -> LDS h2-tile -> dec2]; h/h2 never touch global memory.
//  - scan_add also emits invd + bucket cursors.
//
// Verified MFMA layouts (guide §3): A[m=lane&15][k=(lane>>4)*8+j],
// B[k=(lane>>4)*8+j][n=lane&15], D[row=(lane>>4)*4+r][col=lane&15].

#define THREADS 256

typedef __attribute__((ext_vector_type(8))) short bf16x8;   // 8 bf16 = 4 VGPRs
typedef __attribute__((ext_vector_type(4))) float f32x4;    // acc

__device__ __forceinline__ float bf2f(unsigned short u) {
    unsigned v = ((unsigned)u) << 16;
    return __builtin_bit_cast(float, v);
}
__device__ __forceinline__ unsigned short f2bf(float f) {
    __hip_bfloat16 h = __float2bfloat16(f);   // RNE
    return __builtin_bit_cast(unsigned short, h);
}

// ---------------- CSR build ----------------
__global__ void count_edges(const int* __restrict__ dst, int* __restrict__ cnt, int E) {
    int e = blockIdx.x * blockDim.x + threadIdx.x;
    if (e < E) atomicAdd(&cnt[dst[e]], 1);
}

__global__ void scan_block(const int* __restrict__ cnt, int* __restrict__ offs,
                           int* __restrict__ bsum, int n) {
    __shared__ int tsum[256];
    int t = threadIdx.x;
    int base = blockIdx.x * 1024 + t * 4;
    int v0 = (base + 0 < n) ? cnt[base + 0] : 0;
    int v1 = (base + 1 < n) ? cnt[base + 1] : 0;
    int v2 = (base + 2 < n) ? cnt[base + 2] : 0;
    int v3 = (base + 3 < n) ? cnt[base + 3] : 0;
    int s = v0 + v1 + v2 + v3;
    tsum[t] = s;
    __syncthreads();
    for (int off = 1; off < 256; off <<= 1) {
        int xv = (t >= off) ? tsum[t - off] : 0;
        __syncthreads();
        tsum[t] += xv;
        __syncthreads();
    }
    int excl = tsum[t] - s;
    if (base + 0 < n) offs[base + 0] = excl;
    if (base + 1 < n) offs[base + 1] = excl + v0;
    if (base + 2 < n) offs[base + 2] = excl + v0 + v1;
    if (base + 3 < n) offs[base + 3] = excl + v0 + v1 + v2;
    if (t == 255) bsum[blockIdx.x] = tsum[255];
}

__global__ void scan_partials(int* __restrict__ bsum, int* __restrict__ total, int nb) {
    __shared__ int sm[256];
    int t = threadIdx.x;
    int v = (t < nb) ? bsum[t] : 0;
    sm[t] = v;
    __syncthreads();
    for (int off = 1; off < 256; off <<= 1) {
        int xv = (t >= off) ? sm[t - off] : 0;
        __syncthreads();
        sm[t] += xv;
        __syncthreads();
    }
    if (t < nb) bsum[t] = sm[t] - v;
    if (t == 255) *total = sm[255];
}

// finalize offs; also emit invd and bucket cursors (bcur[b] = offs[b*256])
__global__ void scan_add_fused(int* __restrict__ offs, const int* __restrict__ bsum,
                               const int* __restrict__ total, const int* __restrict__ cnt,
                               float* __restrict__ invd, int* __restrict__ bcur, int n) {
    int i = blockIdx.x * blockDim.x + threadIdx.x;
    if (i < n) {
        int v = offs[i] + bsum[i >> 10];
        offs[i] = v;
        if ((i & 255) == 0) bcur[i >> 8] = v;
        invd[i] = 1.0f / (float)max(cnt[i], 1);
    }
    if (i == 0) offs[n] = *total;
}

// Pass A: partition edges into buckets of 256 consecutive dst nodes.
// 4096 edges/block; LDS histogram -> 1 global atomic per (block,bucket);
// writes int2(src,dst) into the bucket's contiguous region of epair.
__global__ __launch_bounds__(256) void partition_edges(
    const int* __restrict__ src, const int* __restrict__ dst,
    int* __restrict__ bcur, int2* __restrict__ epair, int E) {
    __shared__ int hist[256];
    __shared__ int base[256];
    __shared__ int lcur[256];
    int t = threadIdx.x;
    hist[t] = 0;
    __syncthreads();
    int e0 = blockIdx.x * 4096;
    int myd[16], mys[16];
#pragma unroll
    for (int i = 0; i < 16; ++i) {
        int e = e0 + t + i * 256;
        int d = (e < E) ? dst[e] : -1;
        mys[i] = (e < E) ? src[e] : 0;
        myd[i] = d;
        if (d >= 0) atomicAdd(&hist[d >> 8], 1);
    }
    __syncthreads();
    int h = hist[t];
    if (h > 0) base[t] = atomicAdd(&bcur[t], h);
    lcur[t] = 0;
    __syncthreads();
#pragma unroll
    for (int i = 0; i < 16; ++i) {
        int d = myd[i];
        if (d >= 0) {
            int b = d >> 8;
            int p = atomicAdd(&lcur[b], 1);
            epair[base[b] + p] = make_int2(mys[i], d);
        }
    }
}

// Pass B: one block per bucket. Order the bucket's edges by dst via LDS
// cursors, stage in LDS, write esrc region fully coalesced.
__global__ __launch_bounds__(256) void bucket_fill(
    const int2* __restrict__ epair, const int* __restrict__ offs,
    int* __restrict__ esrc, int N) {
    __shared__ int loff[257];
    __shared__ int ncur[256];
    __shared__ int stage[8192];
    int b = blockIdx.x, t = threadIdx.x;
    int n0 = b << 8;
    int cntn = min(256, N - n0);
    for (int i = t; i <= cntn; i += 256) loff[i] = offs[n0 + i];
    ncur[t] = 0;
    __syncthreads();
    int ebase = loff[0];
    int ecount = loff[cntn] - ebase;
    bool useLds = (ecount <= 8192);
    for (int i = t; i < ecount; i += 256) {
        int2 p = epair[ebase + i];
        int dl = p.y - n0;
        int pos = atomicAdd(&ncur[dl], 1);
        int g = loff[dl] + pos;             // global slot
        if (useLds) stage[g - ebase] = p.x;
        else        esrc[g] = p.x;
    }
    __syncthreads();
    if (useLds)
        for (int i = t; i < ecount; i += 256) esrc[ebase + i] = stage[i];
}

// ---------------- weight pack + x convert ----------------
// Pack fp32 W (eff. K x NOUT) into MFMA B-frag layout bf16:
// dst[(((s*NB + j)*64 + lane)*8 + i] = W[s*32 + (lane>>4)*8 + i][j*16 + (lane&15)]
__device__ __forceinline__ void pack_one(unsigned short* dst,
                                         const float* W0, const float* W1,
                                         int NB, int ksplit, int colsplit,
                                         int ld0, int ld1, int t) {
    int i = t & 7, lane = (t >> 3) & 63, rest = t >> 9;
    int j = rest % NB, s = rest / NB;
    int k = s * 32 + ((lane >> 4) << 3) + i;
    int c = (j << 4) + (lane & 15);
    float v;
    if (c >= colsplit)    v = W1[(size_t)k * ld1 + (c - colsplit)];
    else if (k >= ksplit) v = W1[(size_t)(k - ksplit) * ld1 + c];
    else                  v = W0[(size_t)k * ld0 + c];
    dst[t] = f2bf(v);
}

#define BIG (1 << 30)

__global__ void prep_kernel(const float* __restrict__ W1g, const float* __restrict__ root1,
                            const float* __restrict__ W2g, const float* __restrict__ root2,
                            const float* __restrict__ dw1, const float* __restrict__ dw2,
                            const float* __restrict__ x,
                            unsigned short* __restrict__ Pb1,   // 128x256
                            unsigned short* __restrict__ Pb2,   // 256x128
                            unsigned short* __restrict__ Pd1,   // 64x256
                            unsigned short* __restrict__ Pd2,   // 256x64
                            unsigned short* __restrict__ ab1,   // N x 128, x -> cols 64:128
                            int n) {
    int t = blockIdx.x * blockDim.x + threadIdx.x;
    if (t < 32768) {
        pack_one(Pb1, W1g, root1, 16, 64, BIG, 256, 256, t);
    } else if (t < 65536) {
        pack_one(Pb2, W2g, root2, 8, BIG, 64, 64, 64, t - 32768);
    } else if (t < 81920) {
        pack_one(Pd1, dw1, dw1, 16, BIG, BIG, 256, 256, t - 65536);
    } else if (t < 98304) {
        pack_one(Pd2, dw2, dw2, 4, BIG, BIG, 64, 64, t - 81920);
    } else {
        int u = t - 98304;
        if (u < n * 64) {
            int row = u >> 6, col = u & 63;
            ab1[(size_t)row * 128 + 64 + col] = f2bf(x[(size_t)row * 64 + col]);
        }
    }
}

// ---------------- gathers (bf16 tables, fp32 accumulate) ----------------
__global__ void agg_x_bf16(unsigned short* __restrict__ ab1, const int* __restrict__ esrc,
                           const int* __restrict__ offs, const float* __restrict__ invd,
                           int n) {
    int node = blockIdx.x * 4 + (threadIdx.x >> 6);
    int l = threadIdx.x & 63;
    if (node >= n) return;
    int s = offs[node], e = offs[node + 1];
    float a0 = 0.f, a1 = 0.f, a2 = 0.f, a3 = 0.f;
    int j = s;
    for (; j + 4 <= e; j += 4) {
        int i0 = esrc[j], i1 = esrc[j + 1], i2 = esrc[j + 2], i3 = esrc[j + 3];
        a0 += bf2f(ab1[(size_t)i0 * 128 + 64 + l]);
        a1 += bf2f(ab1[(size_t)i1 * 128 + 64 + l]);
        a2 += bf2f(ab1[(size_t)i2 * 128 + 64 + l]);
        a3 += bf2f(ab1[(size_t)i3 * 128 + 64 + l]);
    }
    for (; j < e; ++j) a0 += bf2f(ab1[(size_t)esrc[j] * 128 + 64 + l]);
    ab1[(size_t)node * 128 + l] = f2bf((a0 + a1 + a2 + a3) * invd[node]);
}

__global__ void agg_z_bf16(const unsigned short* __restrict__ hwroot,
                           const int* __restrict__ esrc, const int* __restrict__ offs,
                           const float* __restrict__ invd, const float* __restrict__ b2,
                           unsigned short* __restrict__ z, int n) {
    int node = blockIdx.x * 4 + (threadIdx.x >> 6);
    int l = threadIdx.x & 63;
    if (node >= n) return;
    int s = offs[node], e = offs[node + 1];
    float a0 = 0.f, a1 = 0.f, a2 = 0.f, a3 = 0.f;
    int j = s;
    for (; j + 4 <= e; j += 4) {
        int i0 = esrc[j], i1 = esrc[j + 1], i2 = esrc[j + 2], i3 = esrc[j + 3];
        a0 += bf2f(hwroot[(size_t)i0 * 128 + l]);
        a1 += bf2f(hwroot[(size_t)i1 * 128 + l]);
        a2 += bf2f(hwroot[(size_t)i2 * 128 + l]);
        a3 += bf2f(hwroot[(size_t)i3 * 128 + l]);
    }
    for (; j < e; ++j) a0 += bf2f(hwroot[(size_t)esrc[j] * 128 + l]);
    float v = (a0 + a1 + a2 + a3) * invd[node]
            + bf2f(hwroot[(size_t)node * 128 + 64 + l]) + b2[l];
    z[(size_t)node * 64 + l] = f2bf(v);
}

// ---------------- fused double-GEMM ----------------
// Stage 1: T = relu(A @ Wp1 + bias1)  (A: n x K1 bf16, T: 64 x 256 tile in LDS)
// Stage 2: C = T @ Wp2 (+ bias2)      (C: n x (NBW2*64))
// 256 threads = 4 waves; M-tile 64. LDS tile padded to 264 cols: stage-2
// ds_read_b128 rows differ by 132 dwords = bank+4 -> 2-way (free).
template <int K1, int NBW2, bool OUTBF>
__global__ __launch_bounds__(256) void gemm_fused(
    const unsigned short* __restrict__ A,
    const unsigned short* __restrict__ Bp1, const float* __restrict__ bias1,
    const unsigned short* __restrict__ Bp2, const float* __restrict__ bias2,
    void* __restrict__ Cv, int n)
{
    constexpr int KS1 = K1 / 32;
    constexpr int N2 = NBW2 * 64;
    constexpr int NB2 = NBW2 * 4;
    __shared__ unsigned short ht[64][264];

    const int m0 = blockIdx.x * 64;
    const int lane = threadIdx.x & 63;
    const int w = threadIdx.x >> 6;
    const int quad = lane >> 4;
    const int l16 = lane & 15;

    // ---- stage 1 ----
    {
        f32x4 acc[4][4] = {};
        const unsigned short* Arow = A + (size_t)(m0 + l16) * K1 + quad * 8;
        for (int s = 0; s < KS1; ++s) {
            bf16x8 a[4];
#pragma unroll
            for (int mb = 0; mb < 4; ++mb)
                a[mb] = *(const bf16x8*)(Arow + (size_t)mb * 16 * K1 + s * 32);
#pragma unroll
            for (int jn = 0; jn < 4; ++jn) {
                int j = w * 4 + jn;
                bf16x8 b = *(const bf16x8*)(Bp1 + ((size_t)(s * 16 + j) * 64 + lane) * 8);
#pragma unroll
                for (int mb = 0; mb < 4; ++mb)
                    acc[mb][jn] = __builtin_amdgcn_mfma_f32_16x16x32_bf16(a[mb], b, acc[mb][jn], 0, 0, 0);
            }
        }
#pragma unroll
        for (int jn = 0; jn < 4; ++jn) {
            int col = (w * 4 + jn) * 16 + l16;
            float bv = bias1[col];
#pragma unroll
            for (int mb = 0; mb < 4; ++mb)
#pragma unroll
                for (int r = 0; r < 4; ++r) {
                    int row = mb * 16 + quad * 4 + r;
                    ht[row][col] = f2bf(fmaxf(acc[mb][jn][r] + bv, 0.f));
                }
        }
    }
    __syncthreads();

    // ---- stage 2 ----
    {
        f32x4 acc[4][NBW2] = {};
        for (int s = 0; s < 8; ++s) {
            bf16x8 a[4];
#pragma unroll
            for (int mb = 0; mb < 4; ++mb)
                a[mb] = *(const bf16x8*)&ht[mb * 16 + l16][s * 32 + quad * 8];
#pragma unroll
            for (int jn = 0; jn < NBW2; ++jn) {
                int j = w * NBW2 + jn;
                bf16x8 b = *(const bf16x8*)(Bp2 + ((size_t)(s * NB2 + j) * 64 + lane) * 8);
#pragma unroll
                for (int mb = 0; mb < 4; ++mb)
                    acc[mb][jn] = __builtin_amdgcn_mfma_f32_16x16x32_bf16(a[mb], b, acc[mb][jn], 0, 0, 0);
            }
        }
#pragma unroll
        for (int jn = 0; jn < NBW2; ++jn) {
            int col = (w * NBW2 + jn) * 16 + l16;
            float bv = bias2 ? bias2[col] : 0.f;
#pragma unroll
            for (int mb = 0; mb < 4; ++mb)
#pragma unroll
                for (int r = 0; r < 4; ++r) {
                    int row = m0 + mb * 16 + quad * 4 + r;
                    if (row < n) {
                        float v = acc[mb][jn][r] + bv;
                        if (OUTBF)
                            ((unsigned short*)Cv)[(size_t)row * N2 + col] = f2bf(v);
                        else
                            ((float*)Cv)[(size_t)row * N2 + col] = v;
                    }
                }
        }
    }
}

extern "C" void kernel_launch(void* const* d_in, const int* in_sizes, int n_in,
                              void* d_out, int out_size, void* d_ws, size_t ws_size,
                              hipStream_t stream) {
    const float* x      = (const float*)d_in[0];
    const int*   ei     = (const int*)d_in[1];
    const float* W1g    = (const float*)d_in[2];   // (8,64,256): [0] = first 16384
    const float* root1  = (const float*)d_in[3];
    const float* b1     = (const float*)d_in[4];
    const float* W2g    = (const float*)d_in[5];   // (8,256,64): [0] = first 16384
    const float* root2  = (const float*)d_in[6];
    const float* b2     = (const float*)d_in[7];
    const float* dw1    = (const float*)d_in[8];
    const float* db1    = (const float*)d_in[9];
    const float* dw2    = (const float*)d_in[10];
    const float* db2    = (const float*)d_in[11];
    float* out = (float*)d_out;

    const int N = in_sizes[0] / 64;
    const int E = in_sizes[1] / 2;
    const int Npad = N + 64;
    const int* srcv = ei;
    const int* dstv = ei + E;

    char* ws = (char*)d_ws;
    auto alloc = [&](size_t bytes) -> void* {
        void* p = (void*)ws;
        ws += (bytes + 255) & ~(size_t)255;
        return p;
    };
    int*   cnt    = (int*)alloc((size_t)N * 4);
    int*   offs   = (int*)alloc((size_t)(N + 1) * 4);
    int*   bsum   = (int*)alloc(1024);
    int*   total  = (int*)alloc(256);
    int*   bcur   = (int*)alloc(1024);               // <=256 buckets
    float* invd   = (float*)alloc((size_t)N * 4);
    int*   esrc   = (int*)alloc((size_t)E * 4);
    int2*  epair  = (int2*)alloc((size_t)E * 8);
    unsigned short* Pb1 = (unsigned short*)alloc(32768 * 2);
    unsigned short* Pb2 = (unsigned short*)alloc(32768 * 2);
    unsigned short* Pd1 = (unsigned short*)alloc(16384 * 2);
    unsigned short* Pd2 = (unsigned short*)alloc(16384 * 2);
    unsigned short* ab1    = (unsigned short*)alloc((size_t)Npad * 128 * 2);  // [agg1 | xb]
    unsigned short* hwroot = (unsigned short*)alloc((size_t)Npad * 128 * 2);
    unsigned short* z      = (unsigned short*)alloc((size_t)Npad * 64 * 2);

    hipMemsetAsync(cnt, 0, (size_t)N * 4, stream);

    int eb = (E + THREADS - 1) / THREADS;
    int nb = (N + THREADS - 1) / THREADS;
    int sb = (N + 1023) / 1024;
    int gb = (N + 63) / 64;
    int pb = (98304 + N * 64 + THREADS - 1) / THREADS;
    int nbkt = (N + 255) / 256;
    int pa = (E + 4095) / 4096;

    // weight pack + x->bf16 (independent of CSR chain)
    prep_kernel<<<pb, THREADS, 0, stream>>>(W1g, root1, W2g, root2, dw1, dw2, x,
                                            Pb1, Pb2, Pd1, Pd2, ab1, N);
    // CSR
    count_edges<<<eb, THREADS, 0, stream>>>(dstv, cnt, E);
    scan_block<<<sb, 256, 0, stream>>>(cnt, offs, bsum, N);
    scan_partials<<<1, 256, 0, stream>>>(bsum, total, sb);
    scan_add_fused<<<nb, THREADS, 0, stream>>>(offs, bsum, total, cnt, invd, bcur, N);
    partition_edges<<<pa, 256, 0, stream>>>(srcv, dstv, bcur, epair, E);
    bucket_fill<<<nbkt, 256, 0, stream>>>(epair, offs, esrc, N);

    // layer 1 agg + fused [L1 GEMM -> L2 projection]
    agg_x_bf16<<<(N + 3) / 4, THREADS, 0, stream>>>(ab1, esrc, offs, invd, N);
    gemm_fused<128, 2, true><<<gb, 256, 0, stream>>>(ab1, Pb1, b1, Pb2, nullptr, hwroot, N);
    // layer 2 gather + epilogue
    agg_z_bf16<<<(N + 3) / 4, THREADS, 0, stream>>>(hwroot, esrc, offs, invd, b2, z, N);
    // fused decoder [dec1 -> dec2]
    gemm_fused<64, 1, false><<<gb, 256, 0, stream>>>(z, Pd1, db1, Pd2, db2, out, N);
}

// Round 7
// 243.090 us; speedup vs baseline: 4.5897x; 1.0671x over previous
//
#include <hip/hip_runtime.h>
#include <hip/hip_bf16.h>

// GraphAE: pseudo == 0 => only W[0] of the 8 spline matrices matters.
// Linearization: mean(h[src])@W2_0 == mean(h[src]@W2_0) -> project before gather.
// Round 7:
//  - gathers: 2 gather-rows per load instr (32 lanes x 4B = 128B row), 4x pair
//    unroll -> 8 edges in flight, half the instructions; cross-slot shfl_xor.
//  - count_edges fused into prep; scan_partials fused into scan_add.
//  - epair packed to one int (src | dl<<20): halves partition/fill traffic.
//
// Verified MFMA layouts (guide §3): A[m=lane&15][k=(lane>>4)*8+j],
// B[k=(lane>>4)*8+j][n=lane&15], D[row=(lane>>4)*4+r][col=lane&15].

#define THREADS 256

typedef __attribute__((ext_vector_type(8))) short bf16x8;   // 8 bf16 = 4 VGPRs
typedef __attribute__((ext_vector_type(4))) float f32x4;    // acc

__device__ __forceinline__ float bf2f(unsigned short u) {
    unsigned v = ((unsigned)u) << 16;
    return __builtin_bit_cast(float, v);
}
__device__ __forceinline__ unsigned short f2bf(float f) {
    __hip_bfloat16 h = __float2bfloat16(f);   // RNE
    return __builtin_bit_cast(unsigned short, h);
}

// ---------------- weight pack ----------------
// Pack fp32 W (eff. K x NOUT) into MFMA B-frag layout bf16:
// dst[(((s*NB + j)*64 + lane)*8 + i] = W[s*32 + (lane>>4)*8 + i][j*16 + (lane&15)]
__device__ __forceinline__ void pack_one(unsigned short* dst,
                                         const float* W0, const float* W1,
                                         int NB, int ksplit, int colsplit,
                                         int ld0, int ld1, int t) {
    int i = t & 7, lane = (t >> 3) & 63, rest = t >> 9;
    int j = rest % NB, s = rest / NB;
    int k = s * 32 + ((lane >> 4) << 3) + i;
    int c = (j << 4) + (lane & 15);
    float v;
    if (c >= colsplit)    v = W1[(size_t)k * ld1 + (c - colsplit)];
    else if (k >= ksplit) v = W1[(size_t)(k - ksplit) * ld1 + c];
    else                  v = W0[(size_t)k * ld0 + c];
    dst[t] = f2bf(v);
}

#define BIG (1 << 30)

// prep: weight packs + x->bf16 + edge counting (fused, disjoint thread ranges)
__global__ void prep_kernel(const float* __restrict__ W1g, const float* __restrict__ root1,
                            const float* __restrict__ W2g, const float* __restrict__ root2,
                            const float* __restrict__ dw1, const float* __restrict__ dw2,
                            const float* __restrict__ x, const int* __restrict__ dstv,
                            int* __restrict__ cnt,
                            unsigned short* __restrict__ Pb1,   // 128x256
                            unsigned short* __restrict__ Pb2,   // 256x128
                            unsigned short* __restrict__ Pd1,   // 64x256
                            unsigned short* __restrict__ Pd2,   // 256x64
                            unsigned short* __restrict__ ab1,   // N x 128, x -> cols 64:128
                            int n, int E) {
    int t = blockIdx.x * blockDim.x + threadIdx.x;
    if (t < 32768) {
        pack_one(Pb1, W1g, root1, 16, 64, BIG, 256, 256, t);
    } else if (t < 65536) {
        pack_one(Pb2, W2g, root2, 8, BIG, 64, 64, 64, t - 32768);
    } else if (t < 81920) {
        pack_one(Pd1, dw1, dw1, 16, BIG, BIG, 256, 256, t - 65536);
    } else if (t < 98304) {
        pack_one(Pd2, dw2, dw2, 4, BIG, BIG, 64, 64, t - 81920);
    } else if (t < 98304 + n * 64) {
        int u = t - 98304;
        int row = u >> 6, col = u & 63;
        ab1[(size_t)row * 128 + 64 + col] = f2bf(x[(size_t)row * 64 + col]);
    } else {
        int e = t - 98304 - n * 64;
        if (e < E) atomicAdd(&cnt[dstv[e]], 1);
    }
}

// ---------------- CSR build ----------------
__global__ void scan_block(const int* __restrict__ cnt, int* __restrict__ offs,
                           int* __restrict__ bsum, int n) {
    __shared__ int tsum[256];
    int t = threadIdx.x;
    int base = blockIdx.x * 1024 + t * 4;
    int v0 = (base + 0 < n) ? cnt[base + 0] : 0;
    int v1 = (base + 1 < n) ? cnt[base + 1] : 0;
    int v2 = (base + 2 < n) ? cnt[base + 2] : 0;
    int v3 = (base + 3 < n) ? cnt[base + 3] : 0;
    int s = v0 + v1 + v2 + v3;
    tsum[t] = s;
    __syncthreads();
    for (int off = 1; off < 256; off <<= 1) {
        int xv = (t >= off) ? tsum[t - off] : 0;
        __syncthreads();
        tsum[t] += xv;
        __syncthreads();
    }
    int excl = tsum[t] - s;
    if (base + 0 < n) offs[base + 0] = excl;
    if (base + 1 < n) offs[base + 1] = excl + v0;
    if (base + 2 < n) offs[base + 2] = excl + v0 + v1;
    if (base + 3 < n) offs[base + 3] = excl + v0 + v1 + v2;
    if (t == 255) bsum[blockIdx.x] = tsum[255];
}

// finalize offs (each block re-scans the <=256 partials in LDS);
// also emit invd and bucket cursors (bcur[b] = offs[b*256]).
__global__ void scan_add2(int* __restrict__ offs, const int* __restrict__ bsum,
                          const int* __restrict__ cnt, float* __restrict__ invd,
                          int* __restrict__ bcur, int n, int sb) {
    __shared__ int sm[256];
    int t = threadIdx.x;
    sm[t] = (t < sb) ? bsum[t] : 0;
    __syncthreads();
    for (int off = 1; off < 256; off <<= 1) {
        int xv = (t >= off) ? sm[t - off] : 0;
        __syncthreads();
        sm[t] += xv;
        __syncthreads();
    }
    int i = blockIdx.x * blockDim.x + t;
    if (i < n) {
        int blk = i >> 10;
        int carry = blk ? sm[blk - 1] : 0;
        int v = offs[i] + carry;
        offs[i] = v;
        if ((i & 255) == 0) bcur[i >> 8] = v;
        invd[i] = 1.0f / (float)max(cnt[i], 1);
    }
    if (i == 0) offs[n] = sm[sb - 1];
}

// Pass A: partition edges into buckets of 256 consecutive dst nodes.
// 4096 edges/block; LDS histogram -> 1 global atomic per (block,bucket);
// writes packed (dl<<20 | src) into the bucket's contiguous region.
__global__ __launch_bounds__(256) void partition_edges(
    const int* __restrict__ src, const int* __restrict__ dst,
    int* __restrict__ bcur, int* __restrict__ epack, int E) {
    __shared__ int hist[256];
    __shared__ int base[256];
    __shared__ int lcur[256];
    int t = threadIdx.x;
    hist[t] = 0;
    __syncthreads();
    int e0 = blockIdx.x * 4096;
    int myd[16], mys[16];
#pragma unroll
    for (int i = 0; i < 16; ++i) {
        int e = e0 + t + i * 256;
        int d = (e < E) ? dst[e] : -1;
        mys[i] = (e < E) ? src[e] : 0;
        myd[i] = d;
        if (d >= 0) atomicAdd(&hist[d >> 8], 1);
    }
    __syncthreads();
    int h = hist[t];
    if (h > 0) base[t] = atomicAdd(&bcur[t], h);
    lcur[t] = 0;
    __syncthreads();
#pragma unroll
    for (int i = 0; i < 16; ++i) {
        int d = myd[i];
        if (d >= 0) {
            int b = d >> 8;
            int p = atomicAdd(&lcur[b], 1);
            epack[base[b] + p] = ((d & 255) << 20) | mys[i];
        }
    }
}

// Pass B: one block per bucket; bucket-local ordering via LDS cursors,
// stage in LDS, coalesced esrc write.
__global__ __launch_bounds__(256) void bucket_fill(
    const int* __restrict__ epack, const int* __restrict__ offs,
    int* __restrict__ esrc, int N) {
    __shared__ int loff[257];
    __shared__ int ncur[256];
    __shared__ int stage[8192];
    int b = blockIdx.x, t = threadIdx.x;
    int n0 = b << 8;
    int cntn = min(256, N - n0);
    for (int i = t; i <= cntn; i += 256) loff[i] = offs[n0 + i];
    ncur[t] = 0;
    __syncthreads();
    int ebase = loff[0];
    int ecount = loff[cntn] - ebase;
    bool useLds = (ecount <= 8192);
    for (int i = t; i < ecount; i += 256) {
        int p = epack[ebase + i];
        int dl = p >> 20;
        int pos = atomicAdd(&ncur[dl], 1);
        int g = loff[dl] + pos;
        int sv = p & 0xFFFFF;
        if (useLds) stage[g - ebase] = sv;
        else        esrc[g] = sv;
    }
    __syncthreads();
    if (useLds)
        for (int i = t; i < ecount; i += 256) esrc[ebase + i] = stage[i];
}

// ---------------- gathers: 2 rows per load instr, 8 edges in flight ----------
// agg1 = mean(x[src]): reads ab1 cols 64:128, writes ab1 cols 0:64.
__global__ void agg_x_pair(unsigned short* __restrict__ ab1, const int* __restrict__ esrc,
                           const int* __restrict__ offs, const float* __restrict__ invd,
                           int n) {
    int node = blockIdx.x * 4 + (threadIdx.x >> 6);
    if (node >= n) return;
    int l = threadIdx.x & 63;
    int slot = l >> 5, c = l & 31;
    const unsigned short* xb = ab1 + 64 + c * 2;
    int s = offs[node], e = offs[node + 1];
    float a0 = 0.f, a1 = 0.f, b0 = 0.f, b1 = 0.f;
    float c0 = 0.f, c1 = 0.f, d0 = 0.f, d1 = 0.f;
    int j = s;
    for (; j + 8 <= e; j += 8) {
        int i0 = esrc[j + slot], i1 = esrc[j + 2 + slot];
        int i2 = esrc[j + 4 + slot], i3 = esrc[j + 6 + slot];
        unsigned v0 = *(const unsigned*)(xb + (size_t)i0 * 128);
        unsigned v1 = *(const unsigned*)(xb + (size_t)i1 * 128);
        unsigned v2 = *(const unsigned*)(xb + (size_t)i2 * 128);
        unsigned v3 = *(const unsigned*)(xb + (size_t)i3 * 128);
        a0 += bf2f((unsigned short)v0); a1 += bf2f((unsigned short)(v0 >> 16));
        b0 += bf2f((unsigned short)v1); b1 += bf2f((unsigned short)(v1 >> 16));
        c0 += bf2f((unsigned short)v2); c1 += bf2f((unsigned short)(v2 >> 16));
        d0 += bf2f((unsigned short)v3); d1 += bf2f((unsigned short)(v3 >> 16));
    }
    for (; j + 2 <= e; j += 2) {
        int i0 = esrc[j + slot];
        unsigned v0 = *(const unsigned*)(xb + (size_t)i0 * 128);
        a0 += bf2f((unsigned short)v0); a1 += bf2f((unsigned short)(v0 >> 16));
    }
    if (j < e && slot == 0) {
        int i0 = esrc[j];
        unsigned v0 = *(const unsigned*)(xb + (size_t)i0 * 128);
        a0 += bf2f((unsigned short)v0); a1 += bf2f((unsigned short)(v0 >> 16));
    }
    float r0 = (a0 + b0) + (c0 + d0), r1 = (a1 + b1) + (c1 + d1);
    r0 += __shfl_xor(r0, 32);
    r1 += __shfl_xor(r1, 32);
    if (slot == 0) {
        float iv = invd[node];
        unsigned o = ((unsigned)f2bf(r1 * iv) << 16) | (unsigned)f2bf(r0 * iv);
        *(unsigned*)(ab1 + (size_t)node * 128 + c * 2) = o;
    }
}

// z = mean(hw[src]) + hroot + b2 ; hwroot N x 128 bf16 (0:64 hw, 64:128 hroot)
__global__ void agg_z_pair(const unsigned short* __restrict__ hwroot,
                           const int* __restrict__ esrc, const int* __restrict__ offs,
                           const float* __restrict__ invd, const float* __restrict__ b2,
                           unsigned short* __restrict__ z, int n) {
    int node = blockIdx.x * 4 + (threadIdx.x >> 6);
    if (node >= n) return;
    int l = threadIdx.x & 63;
    int slot = l >> 5, c = l & 31;
    const unsigned short* hb = hwroot + c * 2;
    int s = offs[node], e = offs[node + 1];
    float a0 = 0.f, a1 = 0.f, b0 = 0.f, b1 = 0.f;
    float c0 = 0.f, c1 = 0.f, d0 = 0.f, d1 = 0.f;
    int j = s;
    for (; j + 8 <= e; j += 8) {
        int i0 = esrc[j + slot], i1 = esrc[j + 2 + slot];
        int i2 = esrc[j + 4 + slot], i3 = esrc[j + 6 + slot];
        unsigned v0 = *(const unsigned*)(hb + (size_t)i0 * 128);
        unsigned v1 = *(const unsigned*)(hb + (size_t)i1 * 128);
        unsigned v2 = *(const unsigned*)(hb + (size_t)i2 * 128);
        unsigned v3 = *(const unsigned*)(hb + (size_t)i3 * 128);
        a0 += bf2f((unsigned short)v0); a1 += bf2f((unsigned short)(v0 >> 16));
        b0 += bf2f((unsigned short)v1); b1 += bf2f((unsigned short)(v1 >> 16));
        c0 += bf2f((unsigned short)v2); c1 += bf2f((unsigned short)(v2 >> 16));
        d0 += bf2f((unsigned short)v3); d1 += bf2f((unsigned short)(v3 >> 16));
    }
    for (; j + 2 <= e; j += 2) {
        int i0 = esrc[j + slot];
        unsigned v0 = *(const unsigned*)(hb + (size_t)i0 * 128);
        a0 += bf2f((unsigned short)v0); a1 += bf2f((unsigned short)(v0 >> 16));
    }
    if (j < e && slot == 0) {
        int i0 = esrc[j];
        unsigned v0 = *(const unsigned*)(hb + (size_t)i0 * 128);
        a0 += bf2f((unsigned short)v0); a1 += bf2f((unsigned short)(v0 >> 16));
    }
    float r0 = (a0 + b0) + (c0 + d0), r1 = (a1 + b1) + (c1 + d1);
    r0 += __shfl_xor(r0, 32);
    r1 += __shfl_xor(r1, 32);
    if (slot == 0) {
        float iv = invd[node];
        unsigned hr = *(const unsigned*)(hwroot + (size_t)node * 128 + 64 + c * 2);
        float v0 = r0 * iv + bf2f((unsigned short)hr) + b2[c * 2];
        float v1 = r1 * iv + bf2f((unsigned short)(hr >> 16)) + b2[c * 2 + 1];
        unsigned o = ((unsigned)f2bf(v1) << 16) | (unsigned)f2bf(v0);
        *(unsigned*)(z + (size_t)node * 64 + c * 2) = o;
    }
}

// ---------------- fused double-GEMM ----------------
// Stage 1: T = relu(A @ Wp1 + bias1)  (A: n x K1 bf16, T: 64 x 256 tile in LDS)
// Stage 2: C = T @ Wp2 (+ bias2)      (C: n x (NBW2*64))
template <int K1, int NBW2, bool OUTBF>
__global__ __launch_bounds__(256) void gemm_fused(
    const unsigned short* __restrict__ A,
    const unsigned short* __restrict__ Bp1, const float* __restrict__ bias1,
    const unsigned short* __restrict__ Bp2, const float* __restrict__ bias2,
    void* __restrict__ Cv, int n)
{
    constexpr int KS1 = K1 / 32;
    constexpr int N2 = NBW2 * 64;
    constexpr int NB2 = NBW2 * 4;
    __shared__ unsigned short ht[64][264];

    const int m0 = blockIdx.x * 64;
    const int lane = threadIdx.x & 63;
    const int w = threadIdx.x >> 6;
    const int quad = lane >> 4;
    const int l16 = lane & 15;

    // ---- stage 1 ----
    {
        f32x4 acc[4][4] = {};
        const unsigned short* Arow = A + (size_t)(m0 + l16) * K1 + quad * 8;
        for (int s = 0; s < KS1; ++s) {
            bf16x8 a[4];
#pragma unroll
            for (int mb = 0; mb < 4; ++mb)
                a[mb] = *(const bf16x8*)(Arow + (size_t)mb * 16 * K1 + s * 32);
#pragma unroll
            for (int jn = 0; jn < 4; ++jn) {
                int j = w * 4 + jn;
                bf16x8 b = *(const bf16x8*)(Bp1 + ((size_t)(s * 16 + j) * 64 + lane) * 8);
#pragma unroll
                for (int mb = 0; mb < 4; ++mb)
                    acc[mb][jn] = __builtin_amdgcn_mfma_f32_16x16x32_bf16(a[mb], b, acc[mb][jn], 0, 0, 0);
            }
        }
#pragma unroll
        for (int jn = 0; jn < 4; ++jn) {
            int col = (w * 4 + jn) * 16 + l16;
            float bv = bias1[col];
#pragma unroll
            for (int mb = 0; mb < 4; ++mb)
#pragma unroll
                for (int r = 0; r < 4; ++r) {
                    int row = mb * 16 + quad * 4 + r;
                    ht[row][col] = f2bf(fmaxf(acc[mb][jn][r] + bv, 0.f));
                }
        }
    }
    __syncthreads();

    // ---- stage 2 ----
    {
        f32x4 acc[4][NBW2] = {};
        for (int s = 0; s < 8; ++s) {
            bf16x8 a[4];
#pragma unroll
            for (int mb = 0; mb < 4; ++mb)
                a[mb] = *(const bf16x8*)&ht[mb * 16 + l16][s * 32 + quad * 8];
#pragma unroll
            for (int jn = 0; jn < NBW2; ++jn) {
                int j = w * NBW2 + jn;
                bf16x8 b = *(const bf16x8*)(Bp2 + ((size_t)(s * NB2 + j) * 64 + lane) * 8);
#pragma unroll
                for (int mb = 0; mb < 4; ++mb)
                    acc[mb][jn] = __builtin_amdgcn_mfma_f32_16x16x32_bf16(a[mb], b, acc[mb][jn], 0, 0, 0);
            }
        }
#pragma unroll
        for (int jn = 0; jn < NBW2; ++jn) {
            int col = (w * NBW2 + jn) * 16 + l16;
            float bv = bias2 ? bias2[col] : 0.f;
#pragma unroll
            for (int mb = 0; mb < 4; ++mb)
#pragma unroll
                for (int r = 0; r < 4; ++r) {
                    int row = m0 + mb * 16 + quad * 4 + r;
                    if (row < n) {
                        float v = acc[mb][jn][r] + bv;
                        if (OUTBF)
                            ((unsigned short*)Cv)[(size_t)row * N2 + col] = f2bf(v);
                        else
                            ((float*)Cv)[(size_t)row * N2 + col] = v;
                    }
                }
        }
    }
}

extern "C" void kernel_launch(void* const* d_in, const int* in_sizes, int n_in,
                              void* d_out, int out_size, void* d_ws, size_t ws_size,
                              hipStream_t stream) {
    const float* x      = (const float*)d_in[0];
    const int*   ei     = (const int*)d_in[1];
    const float* W1g    = (const float*)d_in[2];   // (8,64,256): [0] = first 16384
    const float* root1  = (const float*)d_in[3];
    const float* b1     = (const float*)d_in[4];
    const float* W2g    = (const float*)d_in[5];   // (8,256,64): [0] = first 16384
    const float* root2  = (const float*)d_in[6];
    const float* b2     = (const float*)d_in[7];
    const float* dw1    = (const float*)d_in[8];
    const float* db1    = (const float*)d_in[9];
    const float* dw2    = (const float*)d_in[10];
    const float* db2    = (const float*)d_in[11];
    float* out = (float*)d_out;

    const int N = in_sizes[0] / 64;
    const int E = in_sizes[1] / 2;
    const int Npad = N + 64;
    const int* srcv = ei;
    const int* dstv = ei + E;

    char* ws = (char*)d_ws;
    auto alloc = [&](size_t bytes) -> void* {
        void* p = (void*)ws;
        ws += (bytes + 255) & ~(size_t)255;
        return p;
    };
    int*   cnt    = (int*)alloc((size_t)N * 4);
    int*   offs   = (int*)alloc((size_t)(N + 1) * 4);
    int*   bsum   = (int*)alloc(1024);
    int*   bcur   = (int*)alloc(1024);               // <=256 buckets
    float* invd   = (float*)alloc((size_t)N * 4);
    int*   esrc   = (int*)alloc((size_t)E * 4);
    int*   epack  = (int*)alloc((size_t)E * 4);
    unsigned short* Pb1 = (unsigned short*)alloc(32768 * 2);
    unsigned short* Pb2 = (unsigned short*)alloc(32768 * 2);
    unsigned short* Pd1 = (unsigned short*)alloc(16384 * 2);
    unsigned short* Pd2 = (unsigned short*)alloc(16384 * 2);
    unsigned short* ab1    = (unsigned short*)alloc((size_t)Npad * 128 * 2);  // [agg1 | xb]
    unsigned short* hwroot = (unsigned short*)alloc((size_t)Npad * 128 * 2);
    unsigned short* z      = (unsigned short*)alloc((size_t)Npad * 64 * 2);

    hipMemsetAsync(cnt, 0, (size_t)N * 4, stream);

    int nb = (N + THREADS - 1) / THREADS;
    int sb = (N + 1023) / 1024;
    int gb = (N + 63) / 64;
    int pb = (98304 + N * 64 + E + THREADS - 1) / THREADS;
    int nbkt = (N + 255) / 256;
    int pa = (E + 4095) / 4096;

    // weight pack + x->bf16 + edge count (one kernel)
    prep_kernel<<<pb, THREADS, 0, stream>>>(W1g, root1, W2g, root2, dw1, dw2, x,
                                            dstv, cnt, Pb1, Pb2, Pd1, Pd2, ab1, N, E);
    // CSR
    scan_block<<<sb, 256, 0, stream>>>(cnt, offs, bsum, N);
    scan_add2<<<nb, THREADS, 0, stream>>>(offs, bsum, cnt, invd, bcur, N, sb);
    partition_edges<<<pa, 256, 0, stream>>>(srcv, dstv, bcur, epack, E);
    bucket_fill<<<nbkt, 256, 0, stream>>>(epack, offs, esrc, N);

    // layer 1 agg + fused [L1 GEMM -> L2 projection]
    agg_x_pair<<<(N + 3) / 4, THREADS, 0, stream>>>(ab1, esrc, offs, invd, N);
    gemm_fused<128, 2, true><<<gb, 256, 0, stream>>>(ab1, Pb1, b1, Pb2, nullptr, hwroot, N);
    // layer 2 gather + epilogue
    agg_z_pair<<<(N + 3) / 4, THREADS, 0, stream>>>(hwroot, esrc, offs, invd, b2, z, N);
    // fused decoder [dec1 -> dec2]
    gemm_fused<64, 1, false><<<gb, 256, 0, stream>>>(z, Pd1, db1, Pd2, db2, out, N);
}

// Round 8
// 212.939 us; speedup vs baseline: 5.2396x; 1.1416x over previous
//
#include <hip/hip_runtime.h>
#include <hip/hip_bf16.h>

// GraphAE: pseudo == 0 => only W[0] of the 8 spline matrices matters.
// Linearization: mean(h[src])@W2_0 == mean(h[src]@W2_0) -> project before gather.
// Round 8: kill the 800k random device-scope atomics (count_edges). CSR is now
// bucket-hierarchical: global counts only per 256-node bucket (LDS histograms,
// 256 atomics/block to a 1KB array); per-node offs/invd computed bucket-locally
// in LDS inside bucket_fill2. scan_block/scan_add2 kernels deleted.
//
// Verified MFMA layouts (guide §3): A[m=lane&15][k=(lane>>4)*8+j],
// B[k=(lane>>4)*8+j][n=lane&15], D[row=(lane>>4)*4+r][col=lane&15].

#define THREADS 256

typedef __attribute__((ext_vector_type(8))) short bf16x8;   // 8 bf16 = 4 VGPRs
typedef __attribute__((ext_vector_type(4))) float f32x4;    // acc

__device__ __forceinline__ float bf2f(unsigned short u) {
    unsigned v = ((unsigned)u) << 16;
    return __builtin_bit_cast(float, v);
}
__device__ __forceinline__ unsigned short f2bf(float f) {
    __hip_bfloat16 h = __float2bfloat16(f);   // RNE
    return __builtin_bit_cast(unsigned short, h);
}

// ---------------- weight pack ----------------
// Pack fp32 W (eff. K x NOUT) into MFMA B-frag layout bf16:
// dst[(((s*NB + j)*64 + lane)*8 + i] = W[s*32 + (lane>>4)*8 + i][j*16 + (lane&15)]
__device__ __forceinline__ void pack_one(unsigned short* dst,
                                         const float* W0, const float* W1,
                                         int NB, int ksplit, int colsplit,
                                         int ld0, int ld1, int t) {
    int i = t & 7, lane = (t >> 3) & 63, rest = t >> 9;
    int j = rest % NB, s = rest / NB;
    int k = s * 32 + ((lane >> 4) << 3) + i;
    int c = (j << 4) + (lane & 15);
    float v;
    if (c >= colsplit)    v = W1[(size_t)k * ld1 + (c - colsplit)];
    else if (k >= ksplit) v = W1[(size_t)(k - ksplit) * ld1 + c];
    else                  v = W0[(size_t)k * ld0 + c];
    dst[t] = f2bf(v);
}

#define BIG (1 << 30)

// prep: weight packs + x->bf16 (pack blocks) + bucket histogram (edge blocks)
__global__ void prep_kernel(const float* __restrict__ W1g, const float* __restrict__ root1,
                            const float* __restrict__ W2g, const float* __restrict__ root2,
                            const float* __restrict__ dw1, const float* __restrict__ dw2,
                            const float* __restrict__ x, const int* __restrict__ dstv,
                            int* __restrict__ bcnt,
                            unsigned short* __restrict__ Pb1,   // 128x256
                            unsigned short* __restrict__ Pb2,   // 256x128
                            unsigned short* __restrict__ Pd1,   // 64x256
                            unsigned short* __restrict__ Pd2,   // 256x64
                            unsigned short* __restrict__ ab1,   // N x 128, x -> cols 64:128
                            int n, int E, int pb_pack) {
    if ((int)blockIdx.x >= pb_pack) {
        __shared__ int hist[256];
        int t = threadIdx.x;
        hist[t] = 0;
        __syncthreads();
        int e0 = ((int)blockIdx.x - pb_pack) * 4096;
#pragma unroll
        for (int i = 0; i < 16; ++i) {
            int e = e0 + t + i * 256;
            if (e < E) atomicAdd(&hist[dstv[e] >> 8], 1);
        }
        __syncthreads();
        int h = hist[t];
        if (h) atomicAdd(&bcnt[t], h);
        return;
    }
    int t = blockIdx.x * blockDim.x + threadIdx.x;
    if (t < 32768) {
        pack_one(Pb1, W1g, root1, 16, 64, BIG, 256, 256, t);
    } else if (t < 65536) {
        pack_one(Pb2, W2g, root2, 8, BIG, 64, 64, 64, t - 32768);
    } else if (t < 81920) {
        pack_one(Pd1, dw1, dw1, 16, BIG, BIG, 256, 256, t - 65536);
    } else if (t < 98304) {
        pack_one(Pd2, dw2, dw2, 4, BIG, BIG, 64, 64, t - 81920);
    } else if (t < 98304 + n * 64) {
        int u = t - 98304;
        int row = u >> 6, col = u & 63;
        ab1[(size_t)row * 128 + 64 + col] = f2bf(x[(size_t)row * 64 + col]);
    }
}

// single block: exclusive-scan bucket counts -> bbase/bcur; finalize offs[N]
__global__ void scan_buckets(const int* __restrict__ bcnt, int* __restrict__ bbase,
                             int* __restrict__ bcur, int* __restrict__ offs,
                             int nbkt, int N, int E) {
    __shared__ int sm[256];
    int t = threadIdx.x;
    int v = (t < nbkt) ? bcnt[t] : 0;
    sm[t] = v;
    __syncthreads();
    for (int off = 1; off < 256; off <<= 1) {
        int xv = (t >= off) ? sm[t - off] : 0;
        __syncthreads();
        sm[t] += xv;
        __syncthreads();
    }
    int ex = sm[t] - v;
    bbase[t] = ex;
    bcur[t] = ex;
    if (t == 0) { bbase[256] = E; offs[N] = E; }
}

// Pass A: partition edges into buckets of 256 consecutive dst nodes.
// 4096 edges/block; LDS histogram -> 1 global atomic per (block,bucket);
// writes packed (dl<<20 | src) into the bucket's contiguous region.
__global__ __launch_bounds__(256) void partition_edges(
    const int* __restrict__ src, const int* __restrict__ dst,
    int* __restrict__ bcur, int* __restrict__ epack, int E) {
    __shared__ int hist[256];
    __shared__ int base[256];
    __shared__ int lcur[256];
    int t = threadIdx.x;
    hist[t] = 0;
    __syncthreads();
    int e0 = blockIdx.x * 4096;
    int myd[16], mys[16];
#pragma unroll
    for (int i = 0; i < 16; ++i) {
        int e = e0 + t + i * 256;
        int d = (e < E) ? dst[e] : -1;
        mys[i] = (e < E) ? src[e] : 0;
        myd[i] = d;
        if (d >= 0) atomicAdd(&hist[d >> 8], 1);
    }
    __syncthreads();
    int h = hist[t];
    if (h > 0) base[t] = atomicAdd(&bcur[t], h);
    lcur[t] = 0;
    __syncthreads();
#pragma unroll
    for (int i = 0; i < 16; ++i) {
        int d = myd[i];
        if (d >= 0) {
            int b = d >> 8;
            int p = atomicAdd(&lcur[b], 1);
            epack[base[b] + p] = ((d & 255) << 20) | mys[i];
        }
    }
}

// Pass B: one block per bucket. Local per-node histogram + scan in LDS
// (emits offs and invd), then bucket-local ordering + coalesced esrc write.
__global__ __launch_bounds__(256) void bucket_fill2(
    const int* __restrict__ epack, const int* __restrict__ bbase,
    int* __restrict__ offs, float* __restrict__ invd,
    int* __restrict__ esrc, int N) {
    __shared__ int nh[256];
    __shared__ int loff[256];
    __shared__ int ncur[256];
    __shared__ int stage[8192];
    int b = blockIdx.x, t = threadIdx.x;
    int n0 = b << 8;
    int cntn = min(256, N - n0);
    int ebase = bbase[b];
    int ecount = bbase[b + 1] - ebase;
    nh[t] = 0;
    __syncthreads();
    for (int i = t; i < ecount; i += 256)
        atomicAdd(&nh[epack[ebase + i] >> 20], 1);
    __syncthreads();
    int v = nh[t];
    loff[t] = v;
    __syncthreads();
    for (int off = 1; off < 256; off <<= 1) {
        int xv = (t >= off) ? loff[t - off] : 0;
        __syncthreads();
        loff[t] += xv;
        __syncthreads();
    }
    int ex = loff[t] - v;
    loff[t] = ex;                       // own slot only; sync below
    if (t < cntn) {
        offs[n0 + t] = ebase + ex;
        invd[n0 + t] = 1.0f / (float)max(v, 1);
    }
    ncur[t] = 0;
    __syncthreads();
    bool useLds = (ecount <= 8192);
    for (int i = t; i < ecount; i += 256) {
        int p = epack[ebase + i];
        int dl = p >> 20;
        int pos = atomicAdd(&ncur[dl], 1);
        int g = loff[dl] + pos;         // bucket-local slot
        int sv = p & 0xFFFFF;
        if (useLds) stage[g] = sv;
        else        esrc[ebase + g] = sv;
    }
    __syncthreads();
    if (useLds)
        for (int i = t; i < ecount; i += 256) esrc[ebase + i] = stage[i];
}

// ---------------- gathers: 2 rows per load instr, 8 edges in flight ----------
// agg1 = mean(x[src]): reads ab1 cols 64:128, writes ab1 cols 0:64.
__global__ void agg_x_pair(unsigned short* __restrict__ ab1, const int* __restrict__ esrc,
                           const int* __restrict__ offs, const float* __restrict__ invd,
                           int n) {
    int node = blockIdx.x * 4 + (threadIdx.x >> 6);
    if (node >= n) return;
    int l = threadIdx.x & 63;
    int slot = l >> 5, c = l & 31;
    const unsigned short* xb = ab1 + 64 + c * 2;
    int s = offs[node], e = offs[node + 1];
    float a0 = 0.f, a1 = 0.f, b0 = 0.f, b1 = 0.f;
    float c0 = 0.f, c1 = 0.f, d0 = 0.f, d1 = 0.f;
    int j = s;
    for (; j + 8 <= e; j += 8) {
        int i0 = esrc[j + slot], i1 = esrc[j + 2 + slot];
        int i2 = esrc[j + 4 + slot], i3 = esrc[j + 6 + slot];
        unsigned v0 = *(const unsigned*)(xb + (size_t)i0 * 128);
        unsigned v1 = *(const unsigned*)(xb + (size_t)i1 * 128);
        unsigned v2 = *(const unsigned*)(xb + (size_t)i2 * 128);
        unsigned v3 = *(const unsigned*)(xb + (size_t)i3 * 128);
        a0 += bf2f((unsigned short)v0); a1 += bf2f((unsigned short)(v0 >> 16));
        b0 += bf2f((unsigned short)v1); b1 += bf2f((unsigned short)(v1 >> 16));
        c0 += bf2f((unsigned short)v2); c1 += bf2f((unsigned short)(v2 >> 16));
        d0 += bf2f((unsigned short)v3); d1 += bf2f((unsigned short)(v3 >> 16));
    }
    for (; j + 2 <= e; j += 2) {
        int i0 = esrc[j + slot];
        unsigned v0 = *(const unsigned*)(xb + (size_t)i0 * 128);
        a0 += bf2f((unsigned short)v0); a1 += bf2f((unsigned short)(v0 >> 16));
    }
    if (j < e && slot == 0) {
        int i0 = esrc[j];
        unsigned v0 = *(const unsigned*)(xb + (size_t)i0 * 128);
        a0 += bf2f((unsigned short)v0); a1 += bf2f((unsigned short)(v0 >> 16));
    }
    float r0 = (a0 + b0) + (c0 + d0), r1 = (a1 + b1) + (c1 + d1);
    r0 += __shfl_xor(r0, 32);
    r1 += __shfl_xor(r1, 32);
    if (slot == 0) {
        float iv = invd[node];
        unsigned o = ((unsigned)f2bf(r1 * iv) << 16) | (unsigned)f2bf(r0 * iv);
        *(unsigned*)(ab1 + (size_t)node * 128 + c * 2) = o;
    }
}

// z = mean(hw[src]) + hroot + b2 ; hwroot N x 128 bf16 (0:64 hw, 64:128 hroot)
__global__ void agg_z_pair(const unsigned short* __restrict__ hwroot,
                           const int* __restrict__ esrc, const int* __restrict__ offs,
                           const float* __restrict__ invd, const float* __restrict__ b2,
                           unsigned short* __restrict__ z, int n) {
    int node = blockIdx.x * 4 + (threadIdx.x >> 6);
    if (node >= n) return;
    int l = threadIdx.x & 63;
    int slot = l >> 5, c = l & 31;
    const unsigned short* hb = hwroot + c * 2;
    int s = offs[node], e = offs[node + 1];
    float a0 = 0.f, a1 = 0.f, b0 = 0.f, b1 = 0.f;
    float c0 = 0.f, c1 = 0.f, d0 = 0.f, d1 = 0.f;
    int j = s;
    for (; j + 8 <= e; j += 8) {
        int i0 = esrc[j + slot], i1 = esrc[j + 2 + slot];
        int i2 = esrc[j + 4 + slot], i3 = esrc[j + 6 + slot];
        unsigned v0 = *(const unsigned*)(hb + (size_t)i0 * 128);
        unsigned v1 = *(const unsigned*)(hb + (size_t)i1 * 128);
        unsigned v2 = *(const unsigned*)(hb + (size_t)i2 * 128);
        unsigned v3 = *(const unsigned*)(hb + (size_t)i3 * 128);
        a0 += bf2f((unsigned short)v0); a1 += bf2f((unsigned short)(v0 >> 16));
        b0 += bf2f((unsigned short)v1); b1 += bf2f((unsigned short)(v1 >> 16));
        c0 += bf2f((unsigned short)v2); c1 += bf2f((unsigned short)(v2 >> 16));
        d0 += bf2f((unsigned short)v3); d1 += bf2f((unsigned short)(v3 >> 16));
    }
    for (; j + 2 <= e; j += 2) {
        int i0 = esrc[j + slot];
        unsigned v0 = *(const unsigned*)(hb + (size_t)i0 * 128);
        a0 += bf2f((unsigned short)v0); a1 += bf2f((unsigned short)(v0 >> 16));
    }
    if (j < e && slot == 0) {
        int i0 = esrc[j];
        unsigned v0 = *(const unsigned*)(hb + (size_t)i0 * 128);
        a0 += bf2f((unsigned short)v0); a1 += bf2f((unsigned short)(v0 >> 16));
    }
    float r0 = (a0 + b0) + (c0 + d0), r1 = (a1 + b1) + (c1 + d1);
    r0 += __shfl_xor(r0, 32);
    r1 += __shfl_xor(r1, 32);
    if (slot == 0) {
        float iv = invd[node];
        unsigned hr = *(const unsigned*)(hwroot + (size_t)node * 128 + 64 + c * 2);
        float v0 = r0 * iv + bf2f((unsigned short)hr) + b2[c * 2];
        float v1 = r1 * iv + bf2f((unsigned short)(hr >> 16)) + b2[c * 2 + 1];
        unsigned o = ((unsigned)f2bf(v1) << 16) | (unsigned)f2bf(v0);
        *(unsigned*)(z + (size_t)node * 64 + c * 2) = o;
    }
}

// ---------------- fused double-GEMM ----------------
// Stage 1: T = relu(A @ Wp1 + bias1)  (A: n x K1 bf16, T: 64 x 256 tile in LDS)
// Stage 2: C = T @ Wp2 (+ bias2)      (C: n x (NBW2*64))
template <int K1, int NBW2, bool OUTBF>
__global__ __launch_bounds__(256) void gemm_fused(
    const unsigned short* __restrict__ A,
    const unsigned short* __restrict__ Bp1, const float* __restrict__ bias1,
    const unsigned short* __restrict__ Bp2, const float* __restrict__ bias2,
    void* __restrict__ Cv, int n)
{
    constexpr int KS1 = K1 / 32;
    constexpr int N2 = NBW2 * 64;
    constexpr int NB2 = NBW2 * 4;
    __shared__ unsigned short ht[64][264];

    const int m0 = blockIdx.x * 64;
    const int lane = threadIdx.x & 63;
    const int w = threadIdx.x >> 6;
    const int quad = lane >> 4;
    const int l16 = lane & 15;

    // ---- stage 1 ----
    {
        f32x4 acc[4][4] = {};
        const unsigned short* Arow = A + (size_t)(m0 + l16) * K1 + quad * 8;
        for (int s = 0; s < KS1; ++s) {
            bf16x8 a[4];
#pragma unroll
            for (int mb = 0; mb < 4; ++mb)
                a[mb] = *(const bf16x8*)(Arow + (size_t)mb * 16 * K1 + s * 32);
#pragma unroll
            for (int jn = 0; jn < 4; ++jn) {
                int j = w * 4 + jn;
                bf16x8 b = *(const bf16x8*)(Bp1 + ((size_t)(s * 16 + j) * 64 + lane) * 8);
#pragma unroll
                for (int mb = 0; mb < 4; ++mb)
                    acc[mb][jn] = __builtin_amdgcn_mfma_f32_16x16x32_bf16(a[mb], b, acc[mb][jn], 0, 0, 0);
            }
        }
#pragma unroll
        for (int jn = 0; jn < 4; ++jn) {
            int col = (w * 4 + jn) * 16 + l16;
            float bv = bias1[col];
#pragma unroll
            for (int mb = 0; mb < 4; ++mb)
#pragma unroll
                for (int r = 0; r < 4; ++r) {
                    int row = mb * 16 + quad * 4 + r;
                    ht[row][col] = f2bf(fmaxf(acc[mb][jn][r] + bv, 0.f));
                }
        }
    }
    __syncthreads();

    // ---- stage 2 ----
    {
        f32x4 acc[4][NBW2] = {};
        for (int s = 0; s < 8; ++s) {
            bf16x8 a[4];
#pragma unroll
            for (int mb = 0; mb < 4; ++mb)
                a[mb] = *(const bf16x8*)&ht[mb * 16 + l16][s * 32 + quad * 8];
#pragma unroll
            for (int jn = 0; jn < NBW2; ++jn) {
                int j = w * NBW2 + jn;
                bf16x8 b = *(const bf16x8*)(Bp2 + ((size_t)(s * NB2 + j) * 64 + lane) * 8);
#pragma unroll
                for (int mb = 0; mb < 4; ++mb)
                    acc[mb][jn] = __builtin_amdgcn_mfma_f32_16x16x32_bf16(a[mb], b, acc[mb][jn], 0, 0, 0);
            }
        }
#pragma unroll
        for (int jn = 0; jn < NBW2; ++jn) {
            int col = (w * NBW2 + jn) * 16 + l16;
            float bv = bias2 ? bias2[col] : 0.f;
#pragma unroll
            for (int mb = 0; mb < 4; ++mb)
#pragma unroll
                for (int r = 0; r < 4; ++r) {
                    int row = m0 + mb * 16 + quad * 4 + r;
                    if (row < n) {
                        float v = acc[mb][jn][r] + bv;
                        if (OUTBF)
                            ((unsigned short*)Cv)[(size_t)row * N2 + col] = f2bf(v);
                        else
                            ((float*)Cv)[(size_t)row * N2 + col] = v;
                    }
                }
        }
    }
}

extern "C" void kernel_launch(void* const* d_in, const int* in_sizes, int n_in,
                              void* d_out, int out_size, void* d_ws, size_t ws_size,
                              hipStream_t stream) {
    const float* x      = (const float*)d_in[0];
    const int*   ei     = (const int*)d_in[1];
    const float* W1g    = (const float*)d_in[2];   // (8,64,256): [0] = first 16384
    const float* root1  = (const float*)d_in[3];
    const float* b1     = (const float*)d_in[4];
    const float* W2g    = (const float*)d_in[5];   // (8,256,64): [0] = first 16384
    const float* root2  = (const float*)d_in[6];
    const float* b2     = (const float*)d_in[7];
    const float* dw1    = (const float*)d_in[8];
    const float* db1    = (const float*)d_in[9];
    const float* dw2    = (const float*)d_in[10];
    const float* db2    = (const float*)d_in[11];
    float* out = (float*)d_out;

    const int N = in_sizes[0] / 64;
    const int E = in_sizes[1] / 2;
    const int Npad = N + 64;
    const int* srcv = ei;
    const int* dstv = ei + E;

    char* ws = (char*)d_ws;
    auto alloc = [&](size_t bytes) -> void* {
        void* p = (void*)ws;
        ws += (bytes + 255) & ~(size_t)255;
        return p;
    };
    int*   bcnt   = (int*)alloc(1024);               // per-bucket counts (<=256)
    int*   bbase  = (int*)alloc(1056);               // 257 ints
    int*   bcur   = (int*)alloc(1024);
    int*   offs   = (int*)alloc((size_t)(N + 1) * 4);
    float* invd   = (float*)alloc((size_t)N * 4);
    int*   esrc   = (int*)alloc((size_t)E * 4);
    int*   epack  = (int*)alloc((size_t)E * 4);
    unsigned short* Pb1 = (unsigned short*)alloc(32768 * 2);
    unsigned short* Pb2 = (unsigned short*)alloc(32768 * 2);
    unsigned short* Pd1 = (unsigned short*)alloc(16384 * 2);
    unsigned short* Pd2 = (unsigned short*)alloc(16384 * 2);
    unsigned short* ab1    = (unsigned short*)alloc((size_t)Npad * 128 * 2);  // [agg1 | xb]
    unsigned short* hwroot = (unsigned short*)alloc((size_t)Npad * 128 * 2);
    unsigned short* z      = (unsigned short*)alloc((size_t)Npad * 64 * 2);

    hipMemsetAsync(bcnt, 0, 1024, stream);

    int gb = (N + 63) / 64;
    int nbkt = (N + 255) / 256;
    int pa = (E + 4095) / 4096;
    int pb_pack = (98304 + N * 64 + THREADS - 1) / THREADS;

    // packs + x->bf16 + bucket histogram (one kernel, disjoint block ranges)
    prep_kernel<<<pb_pack + pa, THREADS, 0, stream>>>(
        W1g, root1, W2g, root2, dw1, dw2, x, dstv, bcnt,
        Pb1, Pb2, Pd1, Pd2, ab1, N, E, pb_pack);
    // bucket-level CSR
    scan_buckets<<<1, 256, 0, stream>>>(bcnt, bbase, bcur, offs, nbkt, N, E);
    partition_edges<<<pa, 256, 0, stream>>>(srcv, dstv, bcur, epack, E);
    bucket_fill2<<<nbkt, 256, 0, stream>>>(epack, bbase, offs, invd, esrc, N);

    // layer 1 agg + fused [L1 GEMM -> L2 projection]
    agg_x_pair<<<(N + 3) / 4, THREADS, 0, stream>>>(ab1, esrc, offs, invd, N);
    gemm_fused<128, 2, true><<<gb, 256, 0, stream>>>(ab1, Pb1, b1, Pb2, nullptr, hwroot, N);
    // layer 2 gather + epilogue
    agg_z_pair<<<(N + 3) / 4, THREADS, 0, stream>>>(hwroot, esrc, offs, invd, b2, z, N);
    // fused decoder [dec1 -> dec2]
    gemm_fused<64, 1, false><<<gb, 256, 0, stream>>>(z, Pd1, db1, Pd2, db2, out, N);
}

// Round 9
// 208.591 us; speedup vs baseline: 5.3488x; 1.0208x over previous
//
#include <hip/hip_runtime.h>
#include <hip/hip_bf16.h>

// GraphAE: pseudo == 0 => only W[0] of the 8 spline matrices matters.
// Linearization: mean(h[src])@W2_0 == mean(h[src]@W2_0) -> project before gather.
// Round 9:
//  - gathers: 8B/lane loads (4 edges per wave-instr), 16-edge unroll ->
//    4x8B in flight per thread, half the instructions per edge; shfl_xor(16,32).
//  - scan_buckets deleted: partition/fill re-scan the 1KB bcnt locally in LDS.
//  - prep x->bf16 convert vectorized (float4 -> 8B packed store).
//
// Verified MFMA layouts (guide §3): A[m=lane&15][k=(lane>>4)*8+j],
// B[k=(lane>>4)*8+j][n=lane&15], D[row=(lane>>4)*4+r][col=lane&15].

#define THREADS 256

typedef __attribute__((ext_vector_type(8))) short bf16x8;   // 8 bf16 = 4 VGPRs
typedef __attribute__((ext_vector_type(4))) float f32x4;    // acc

__device__ __forceinline__ float bf2f(unsigned short u) {
    unsigned v = ((unsigned)u) << 16;
    return __builtin_bit_cast(float, v);
}
__device__ __forceinline__ unsigned short f2bf(float f) {
    __hip_bfloat16 h = __float2bfloat16(f);   // RNE
    return __builtin_bit_cast(unsigned short, h);
}
__device__ __forceinline__ void acc4(float* f, uint2 v) {
    f[0] += bf2f((unsigned short)v.x);
    f[1] += bf2f((unsigned short)(v.x >> 16));
    f[2] += bf2f((unsigned short)v.y);
    f[3] += bf2f((unsigned short)(v.y >> 16));
}

// ---------------- weight pack ----------------
// Pack fp32 W (eff. K x NOUT) into MFMA B-frag layout bf16:
// dst[(((s*NB + j)*64 + lane)*8 + i] = W[s*32 + (lane>>4)*8 + i][j*16 + (lane&15)]
__device__ __forceinline__ void pack_one(unsigned short* dst,
                                         const float* W0, const float* W1,
                                         int NB, int ksplit, int colsplit,
                                         int ld0, int ld1, int t) {
    int i = t & 7, lane = (t >> 3) & 63, rest = t >> 9;
    int j = rest % NB, s = rest / NB;
    int k = s * 32 + ((lane >> 4) << 3) + i;
    int c = (j << 4) + (lane & 15);
    float v;
    if (c >= colsplit)    v = W1[(size_t)k * ld1 + (c - colsplit)];
    else if (k >= ksplit) v = W1[(size_t)(k - ksplit) * ld1 + c];
    else                  v = W0[(size_t)k * ld0 + c];
    dst[t] = f2bf(v);
}

#define BIG (1 << 30)

// prep: weight packs + x->bf16 (vectorized) + bucket histogram (edge blocks)
__global__ void prep_kernel(const float* __restrict__ W1g, const float* __restrict__ root1,
                            const float* __restrict__ W2g, const float* __restrict__ root2,
                            const float* __restrict__ dw1, const float* __restrict__ dw2,
                            const float* __restrict__ x, const int* __restrict__ dstv,
                            int* __restrict__ bcnt,
                            unsigned short* __restrict__ Pb1,   // 128x256
                            unsigned short* __restrict__ Pb2,   // 256x128
                            unsigned short* __restrict__ Pd1,   // 64x256
                            unsigned short* __restrict__ Pd2,   // 256x64
                            unsigned short* __restrict__ ab1,   // N x 128, x -> cols 64:128
                            int n, int E, int pb_pack) {
    if ((int)blockIdx.x >= pb_pack) {
        __shared__ int hist[256];
        int t = threadIdx.x;
        hist[t] = 0;
        __syncthreads();
        int e0 = ((int)blockIdx.x - pb_pack) * 4096;
#pragma unroll
        for (int i = 0; i < 16; ++i) {
            int e = e0 + t + i * 256;
            if (e < E) atomicAdd(&hist[dstv[e] >> 8], 1);
        }
        __syncthreads();
        int h = hist[t];
        if (h) atomicAdd(&bcnt[t], h);
        return;
    }
    int t = blockIdx.x * blockDim.x + threadIdx.x;
    if (t < 32768) {
        pack_one(Pb1, W1g, root1, 16, 64, BIG, 256, 256, t);
    } else if (t < 65536) {
        pack_one(Pb2, W2g, root2, 8, BIG, 64, 64, 64, t - 32768);
    } else if (t < 81920) {
        pack_one(Pd1, dw1, dw1, 16, BIG, BIG, 256, 256, t - 65536);
    } else if (t < 98304) {
        pack_one(Pd2, dw2, dw2, 4, BIG, BIG, 64, 64, t - 81920);
    } else if (t < 98304 + n * 16) {
        int u = t - 98304;
        int row = u >> 4, c4 = (u & 15) * 4;
        float4 v = *(const float4*)(x + (size_t)row * 64 + c4);
        unsigned lo = (unsigned)f2bf(v.x) | ((unsigned)f2bf(v.y) << 16);
        unsigned hi = (unsigned)f2bf(v.z) | ((unsigned)f2bf(v.w) << 16);
        uint2 o; o.x = lo; o.y = hi;
        *(uint2*)(ab1 + (size_t)row * 128 + 64 + c4) = o;
    }
}

// Pass A: partition edges into buckets of 256 consecutive dst nodes.
// Computes bucket bases via local LDS scan of bcnt; bcur are 0-based cursors.
__global__ __launch_bounds__(256) void partition_edges(
    const int* __restrict__ src, const int* __restrict__ dst,
    const int* __restrict__ bcnt, int* __restrict__ bcur,
    int* __restrict__ epack, int E) {
    __shared__ int hist[256];
    __shared__ int base[256];
    __shared__ int lcur[256];
    __shared__ int bb[256];
    int t = threadIdx.x;
    hist[t] = 0;
    __syncthreads();
    int e0 = blockIdx.x * 4096;
    int myd[16], mys[16];
#pragma unroll
    for (int i = 0; i < 16; ++i) {
        int e = e0 + t + i * 256;
        int d = (e < E) ? dst[e] : -1;
        mys[i] = (e < E) ? src[e] : 0;
        myd[i] = d;
        if (d >= 0) atomicAdd(&hist[d >> 8], 1);
    }
    // local exclusive scan of bcnt -> bucket bases
    int cb = bcnt[t];
    bb[t] = cb;
    __syncthreads();
    for (int off = 1; off < 256; off <<= 1) {
        int xv = (t >= off) ? bb[t - off] : 0;
        __syncthreads();
        bb[t] += xv;
        __syncthreads();
    }
    int bbase_t = bb[t] - cb;
    int h = hist[t];
    if (h > 0) base[t] = bbase_t + atomicAdd(&bcur[t], h);
    lcur[t] = 0;
    __syncthreads();
#pragma unroll
    for (int i = 0; i < 16; ++i) {
        int d = myd[i];
        if (d >= 0) {
            int b = d >> 8;
            int p = atomicAdd(&lcur[b], 1);
            epack[base[b] + p] = ((d & 255) << 20) | mys[i];
        }
    }
}

// Pass B: one block per bucket. Local per-node histogram + scan in LDS
// (emits offs and invd), then bucket-local ordering + coalesced esrc write.
__global__ __launch_bounds__(256) void bucket_fill2(
    const int* __restrict__ epack, const int* __restrict__ bcnt,
    int* __restrict__ offs, float* __restrict__ invd,
    int* __restrict__ esrc, int N) {
    __shared__ int sb_[256];
    __shared__ int nh[256];
    __shared__ int loff[256];
    __shared__ int ncur[256];
    __shared__ int stage[8192];
    int b = blockIdx.x, t = threadIdx.x;
    int n0 = b << 8;
    int cntn = min(256, N - n0);
    // bucket base via local scan of bcnt
    int cb = bcnt[t];
    sb_[t] = cb;
    __syncthreads();
    for (int off = 1; off < 256; off <<= 1) {
        int xv = (t >= off) ? sb_[t - off] : 0;
        __syncthreads();
        sb_[t] += xv;
        __syncthreads();
    }
    int ebase = b ? sb_[b - 1] : 0;
    int ecount = sb_[b] - ebase;
    if (b == 0 && t == 0) offs[N] = sb_[255];
    nh[t] = 0;
    __syncthreads();
    for (int i = t; i < ecount; i += 256)
        atomicAdd(&nh[epack[ebase + i] >> 20], 1);
    __syncthreads();
    int v = nh[t];
    loff[t] = v;
    __syncthreads();
    for (int off = 1; off < 256; off <<= 1) {
        int xv = (t >= off) ? loff[t - off] : 0;
        __syncthreads();
        loff[t] += xv;
        __syncthreads();
    }
    int ex = loff[t] - v;
    loff[t] = ex;
    if (t < cntn) {
        offs[n0 + t] = ebase + ex;
        invd[n0 + t] = 1.0f / (float)max(v, 1);
    }
    ncur[t] = 0;
    __syncthreads();
    bool useLds = (ecount <= 8192);
    for (int i = t; i < ecount; i += 256) {
        int p = epack[ebase + i];
        int dl = p >> 20;
        int pos = atomicAdd(&ncur[dl], 1);
        int g = loff[dl] + pos;         // bucket-local slot
        int sv = p & 0xFFFFF;
        if (useLds) stage[g] = sv;
        else        esrc[ebase + g] = sv;
    }
    __syncthreads();
    if (useLds)
        for (int i = t; i < ecount; i += 256) esrc[ebase + i] = stage[i];
}

// ---------------- gathers: 8B/lane, 4 edges per wave-instr, 16-edge unroll ----
// lane = slot(4) x c(16); lane loads features [c*4, c*4+4) of edge (j+slot).
// agg1 = mean(x[src]): reads ab1 cols 64:128, writes ab1 cols 0:64.
__global__ void agg_x4(unsigned short* __restrict__ ab1, const int* __restrict__ esrc,
                       const int* __restrict__ offs, const float* __restrict__ invd,
                       int n) {
    int node = blockIdx.x * 4 + (threadIdx.x >> 6);
    if (node >= n) return;
    int l = threadIdx.x & 63;
    int slot = l >> 4, c = l & 15;
    const unsigned short* xb = ab1 + 64 + c * 4;
    int s = offs[node], e = offs[node + 1];
    float a0[4] = {}, a1[4] = {}, a2[4] = {}, a3[4] = {};
    int j = s;
    for (; j + 16 <= e; j += 16) {
        int i0 = esrc[j + slot],      i1 = esrc[j + 4 + slot];
        int i2 = esrc[j + 8 + slot],  i3 = esrc[j + 12 + slot];
        uint2 v0 = *(const uint2*)(xb + (size_t)i0 * 128);
        uint2 v1 = *(const uint2*)(xb + (size_t)i1 * 128);
        uint2 v2 = *(const uint2*)(xb + (size_t)i2 * 128);
        uint2 v3 = *(const uint2*)(xb + (size_t)i3 * 128);
        acc4(a0, v0); acc4(a1, v1); acc4(a2, v2); acc4(a3, v3);
    }
    for (; j + 4 <= e; j += 4) {
        int i0 = esrc[j + slot];
        uint2 v0 = *(const uint2*)(xb + (size_t)i0 * 128);
        acc4(a0, v0);
    }
    int rem = e - j;
    if (slot < rem) {
        int i0 = esrc[j + slot];
        uint2 v0 = *(const uint2*)(xb + (size_t)i0 * 128);
        acc4(a1, v0);
    }
    float r[4];
#pragma unroll
    for (int k = 0; k < 4; ++k) {
        r[k] = (a0[k] + a1[k]) + (a2[k] + a3[k]);
        r[k] += __shfl_xor(r[k], 16);
        r[k] += __shfl_xor(r[k], 32);
    }
    if (slot == 0) {
        float iv = invd[node];
        unsigned lo = (unsigned)f2bf(r[0] * iv) | ((unsigned)f2bf(r[1] * iv) << 16);
        unsigned hi = (unsigned)f2bf(r[2] * iv) | ((unsigned)f2bf(r[3] * iv) << 16);
        uint2 o; o.x = lo; o.y = hi;
        *(uint2*)(ab1 + (size_t)node * 128 + c * 4) = o;
    }
}

// z = mean(hw[src]) + hroot + b2 ; hwroot N x 128 bf16 (0:64 hw, 64:128 hroot)
__global__ void agg_z4(const unsigned short* __restrict__ hwroot,
                       const int* __restrict__ esrc, const int* __restrict__ offs,
                       const float* __restrict__ invd, const float* __restrict__ b2,
                       unsigned short* __restrict__ z, int n) {
    int node = blockIdx.x * 4 + (threadIdx.x >> 6);
    if (node >= n) return;
    int l = threadIdx.x & 63;
    int slot = l >> 4, c = l & 15;
    const unsigned short* hb = hwroot + c * 4;
    int s = offs[node], e = offs[node + 1];
    float a0[4] = {}, a1[4] = {}, a2[4] = {}, a3[4] = {};
    int j = s;
    for (; j + 16 <= e; j += 16) {
        int i0 = esrc[j + slot],      i1 = esrc[j + 4 + slot];
        int i2 = esrc[j + 8 + slot],  i3 = esrc[j + 12 + slot];
        uint2 v0 = *(const uint2*)(hb + (size_t)i0 * 128);
        uint2 v1 = *(const uint2*)(hb + (size_t)i1 * 128);
        uint2 v2 = *(const uint2*)(hb + (size_t)i2 * 128);
        uint2 v3 = *(const uint2*)(hb + (size_t)i3 * 128);
        acc4(a0, v0); acc4(a1, v1); acc4(a2, v2); acc4(a3, v3);
    }
    for (; j + 4 <= e; j += 4) {
        int i0 = esrc[j + slot];
        uint2 v0 = *(const uint2*)(hb + (size_t)i0 * 128);
        acc4(a0, v0);
    }
    int rem = e - j;
    if (slot < rem) {
        int i0 = esrc[j + slot];
        uint2 v0 = *(const uint2*)(hb + (size_t)i0 * 128);
        acc4(a1, v0);
    }
    float r[4];
#pragma unroll
    for (int k = 0; k < 4; ++k) {
        r[k] = (a0[k] + a1[k]) + (a2[k] + a3[k]);
        r[k] += __shfl_xor(r[k], 16);
        r[k] += __shfl_xor(r[k], 32);
    }
    if (slot == 0) {
        float iv = invd[node];
        uint2 hr = *(const uint2*)(hwroot + (size_t)node * 128 + 64 + c * 4);
        float v0 = r[0] * iv + bf2f((unsigned short)hr.x) + b2[c * 4 + 0];
        float v1 = r[1] * iv + bf2f((unsigned short)(hr.x >> 16)) + b2[c * 4 + 1];
        float v2 = r[2] * iv + bf2f((unsigned short)hr.y) + b2[c * 4 + 2];
        float v3 = r[3] * iv + bf2f((unsigned short)(hr.y >> 16)) + b2[c * 4 + 3];
        unsigned lo = (unsigned)f2bf(v0) | ((unsigned)f2bf(v1) << 16);
        unsigned hi = (unsigned)f2bf(v2) | ((unsigned)f2bf(v3) << 16);
        uint2 o; o.x = lo; o.y = hi;
        *(uint2*)(z + (size_t)node * 64 + c * 4) = o;
    }
}

// ---------------- fused double-GEMM ----------------
// Stage 1: T = relu(A @ Wp1 + bias1)  (A: n x K1 bf16, T: 64 x 256 tile in LDS)
// Stage 2: C = T @ Wp2 (+ bias2)      (C: n x (NBW2*64))
template <int K1, int NBW2, bool OUTBF>
__global__ __launch_bounds__(256) void gemm_fused(
    const unsigned short* __restrict__ A,
    const unsigned short* __restrict__ Bp1, const float* __restrict__ bias1,
    const unsigned short* __restrict__ Bp2, const float* __restrict__ bias2,
    void* __restrict__ Cv, int n)
{
    constexpr int KS1 = K1 / 32;
    constexpr int N2 = NBW2 * 64;
    constexpr int NB2 = NBW2 * 4;
    __shared__ unsigned short ht[64][264];

    const int m0 = blockIdx.x * 64;
    const int lane = threadIdx.x & 63;
    const int w = threadIdx.x >> 6;
    const int quad = lane >> 4;
    const int l16 = lane & 15;

    // ---- stage 1 ----
    {
        f32x4 acc[4][4] = {};
        const unsigned short* Arow = A + (size_t)(m0 + l16) * K1 + quad * 8;
        for (int s = 0; s < KS1; ++s) {
            bf16x8 a[4];
#pragma unroll
            for (int mb = 0; mb < 4; ++mb)
                a[mb] = *(const bf16x8*)(Arow + (size_t)mb * 16 * K1 + s * 32);
#pragma unroll
            for (int jn = 0; jn < 4; ++jn) {
                int j = w * 4 + jn;
                bf16x8 b = *(const bf16x8*)(Bp1 + ((size_t)(s * 16 + j) * 64 + lane) * 8);
#pragma unroll
                for (int mb = 0; mb < 4; ++mb)
                    acc[mb][jn] = __builtin_amdgcn_mfma_f32_16x16x32_bf16(a[mb], b, acc[mb][jn], 0, 0, 0);
            }
        }
#pragma unroll
        for (int jn = 0; jn < 4; ++jn) {
            int col = (w * 4 + jn) * 16 + l16;
            float bv = bias1[col];
#pragma unroll
            for (int mb = 0; mb < 4; ++mb)
#pragma unroll
                for (int r = 0; r < 4; ++r) {
                    int row = mb * 16 + quad * 4 + r;
                    ht[row][col] = f2bf(fmaxf(acc[mb][jn][r] + bv, 0.f));
                }
        }
    }
    __syncthreads();

    // ---- stage 2 ----
    {
        f32x4 acc[4][NBW2] = {};
        for (int s = 0; s < 8; ++s) {
            bf16x8 a[4];
#pragma unroll
            for (int mb = 0; mb < 4; ++mb)
                a[mb] = *(const bf16x8*)&ht[mb * 16 + l16][s * 32 + quad * 8];
#pragma unroll
            for (int jn = 0; jn < NBW2; ++jn) {
                int j = w * NBW2 + jn;
                bf16x8 b = *(const bf16x8*)(Bp2 + ((size_t)(s * NB2 + j) * 64 + lane) * 8);
#pragma unroll
                for (int mb = 0; mb < 4; ++mb)
                    acc[mb][jn] = __builtin_amdgcn_mfma_f32_16x16x32_bf16(a[mb], b, acc[mb][jn], 0, 0, 0);
            }
        }
#pragma unroll
        for (int jn = 0; jn < NBW2; ++jn) {
            int col = (w * NBW2 + jn) * 16 + l16;
            float bv = bias2 ? bias2[col] : 0.f;
#pragma unroll
            for (int mb = 0; mb < 4; ++mb)
#pragma unroll
                for (int r = 0; r < 4; ++r) {
                    int row = m0 + mb * 16 + quad * 4 + r;
                    if (row < n) {
                        float v = acc[mb][jn][r] + bv;
                        if (OUTBF)
                            ((unsigned short*)Cv)[(size_t)row * N2 + col] = f2bf(v);
                        else
                            ((float*)Cv)[(size_t)row * N2 + col] = v;
                    }
                }
        }
    }
}

extern "C" void kernel_launch(void* const* d_in, const int* in_sizes, int n_in,
                              void* d_out, int out_size, void* d_ws, size_t ws_size,
                              hipStream_t stream) {
    const float* x      = (const float*)d_in[0];
    const int*   ei     = (const int*)d_in[1];
    const float* W1g    = (const float*)d_in[2];   // (8,64,256): [0] = first 16384
    const float* root1  = (const float*)d_in[3];
    const float* b1     = (const float*)d_in[4];
    const float* W2g    = (const float*)d_in[5];   // (8,256,64): [0] = first 16384
    const float* root2  = (const float*)d_in[6];
    const float* b2     = (const float*)d_in[7];
    const float* dw1    = (const float*)d_in[8];
    const float* db1    = (const float*)d_in[9];
    const float* dw2    = (const float*)d_in[10];
    const float* db2    = (const float*)d_in[11];
    float* out = (float*)d_out;

    const int N = in_sizes[0] / 64;
    const int E = in_sizes[1] / 2;
    const int Npad = N + 64;
    const int* srcv = ei;
    const int* dstv = ei + E;

    char* ws = (char*)d_ws;
    auto alloc = [&](size_t bytes) -> void* {
        void* p = (void*)ws;
        ws += (bytes + 255) & ~(size_t)255;
        return p;
    };
    int*   bcnt   = (int*)alloc(1024);               // per-bucket counts (256)
    int*   bcur   = (int*)alloc(1024);               // 0-based bucket cursors
    int*   offs   = (int*)alloc((size_t)(N + 1) * 4);
    float* invd   = (float*)alloc((size_t)N * 4);
    int*   esrc   = (int*)alloc((size_t)E * 4);
    int*   epack  = (int*)alloc((size_t)E * 4);
    unsigned short* Pb1 = (unsigned short*)alloc(32768 * 2);
    unsigned short* Pb2 = (unsigned short*)alloc(32768 * 2);
    unsigned short* Pd1 = (unsigned short*)alloc(16384 * 2);
    unsigned short* Pd2 = (unsigned short*)alloc(16384 * 2);
    unsigned short* ab1    = (unsigned short*)alloc((size_t)Npad * 128 * 2);  // [agg1 | xb]
    unsigned short* hwroot = (unsigned short*)alloc((size_t)Npad * 128 * 2);
    unsigned short* z      = (unsigned short*)alloc((size_t)Npad * 64 * 2);

    hipMemsetAsync(bcnt, 0, 2048, stream);           // bcnt + bcur (adjacent)

    int gb = (N + 63) / 64;
    int nbkt = (N + 255) / 256;
    int pa = (E + 4095) / 4096;
    int pb_pack = (98304 + N * 16 + THREADS - 1) / THREADS;

    // packs + x->bf16 + bucket histogram (one kernel, disjoint block ranges)
    prep_kernel<<<pb_pack + pa, THREADS, 0, stream>>>(
        W1g, root1, W2g, root2, dw1, dw2, x, dstv, bcnt,
        Pb1, Pb2, Pd1, Pd2, ab1, N, E, pb_pack);
    // bucket-level CSR (bases computed locally from bcnt in each kernel)
    partition_edges<<<pa, 256, 0, stream>>>(srcv, dstv, bcnt, bcur, epack, E);
    bucket_fill2<<<nbkt, 256, 0, stream>>>(epack, bcnt, offs, invd, esrc, N);

    // layer 1 agg + fused [L1 GEMM -> L2 projection]
    agg_x4<<<(N + 3) / 4, THREADS, 0, stream>>>(ab1, esrc, offs, invd, N);
    gemm_fused<128, 2, true><<<gb, 256, 0, stream>>>(ab1, Pb1, b1, Pb2, nullptr, hwroot, N);
    // layer 2 gather + epilogue
    agg_z4<<<(N + 3) / 4, THREADS, 0, stream>>>(hwroot, esrc, offs, invd, b2, z, N);
    // fused decoder [dec1 -> dec2]
    gemm_fused<64, 1, false><<<gb, 256, 0, stream>>>(z, Pd1, db1, Pd2, db2, out, N);
}